// Round 12
// baseline (200.667 us; speedup 1.0000x reference)
//
#include <hip/hip_runtime.h>
#include <hip/hip_bf16.h>

#define HH 8
#define KK 4
#define CC 256
#define TT 8
#define LQV 9216        // Lq == Lv (fixed problem shape)

typedef __attribute__((ext_vector_type(8))) short bf16x8;
typedef __attribute__((ext_vector_type(4))) float f32x4;

#define MFMA16(a, b, c) __builtin_amdgcn_mfma_f32_16x16x32_bf16(a, b, c, 0, 0, 0)

__device__ __forceinline__ unsigned short f2bf(float f) {
    union { float f; unsigned u; } v; v.f = f;
    unsigned r = v.u + 0x7fffu + ((v.u >> 16) & 1u);
    return (unsigned short)(r >> 16);
}
__device__ __forceinline__ float bf2f(unsigned short s) {
    union { unsigned u; float f; } v; v.u = ((unsigned)s) << 16;
    return v.f;
}

// ---------------------------------------------------------------------------
// K0: build bf16-transposed weights
// ---------------------------------------------------------------------------
__global__ void k0_prep(const float* __restrict__ Wv, const float* __restrict__ Wout,
                        const float* __restrict__ Woff, const float* __restrict__ Wattn,
                        unsigned short* __restrict__ WvT, unsigned short* __restrict__ WoutT,
                        unsigned short* __restrict__ WoaT)
{
    int o = blockIdx.x * 256 + threadIdx.x;
    if (o < 65536) { int d = o >> 8, c = o & 255; WvT[o]   = f2bf(Wv[c * 256 + d]);   return; }
    o -= 65536;
    if (o < 65536) { int d = o >> 8, c = o & 255; WoutT[o] = f2bf(Wout[c * 256 + d]); return; }
    o -= 65536;
    if (o < 16384) {
        int n = o >> 8, c = o & 255;
        WoaT[o] = f2bf(n < 32 ? Woff[c * 32 + n] : Wattn[c * 32 + (n - 32)]);
    }
}

// ---------------------------------------------------------------------------
// K1b: offsets/logits GEMM fused with softmax -> coef/amask/flags
//   (byte-identical to r11, verified)
// ---------------------------------------------------------------------------
__launch_bounds__(256, 2)
__global__ void k1b_offcoef(const float* __restrict__ queries, const unsigned short* __restrict__ WoaT,
                            const float* __restrict__ b_off, const float* __restrict__ b_attn,
                            const int* __restrict__ idx_q, const float* __restrict__ t_ref_q,
                            float* __restrict__ coefW, int* __restrict__ amaskW,
                            int* __restrict__ flags)
{
    __shared__ __attribute__((aligned(16))) char smem[128 * 65 * 4];   // 33.3 KB union
    unsigned short* A_s = (unsigned short*)smem;                 // [128][40]
    unsigned short* B_s = (unsigned short*)(smem + 128 * 40 * 2); // [64][40]
    float* olog = (float*)smem;                                  // [128][65]

    const int tid = threadIdx.x;
    const int q0 = blockIdx.x * 128;
    const int wid = tid >> 6, l = tid & 63;
    const int wm = wid >> 1, wn = wid & 1;

    f32x4 acc[4][2];
    #pragma unroll
    for (int i = 0; i < 4; ++i)
        #pragma unroll
        for (int j = 0; j < 2; ++j) acc[i][j] = (f32x4){0.f, 0.f, 0.f, 0.f};

    const int arow = tid >> 1, ahalf = tid & 1;      // A stage: 16 f32 each
    const int brow = tid >> 2, bq = tid & 3;         // B stage: 8 bf16 each
    const float* asrc = queries + (size_t)(q0 + arow) * CC + ahalf * 16;

    for (int ks = 0; ks < 8; ++ks) {
        const int k0 = ks * 32;
        {   // stage A (f32 -> bf16)
            float4 v0 = *(const float4*)(asrc + k0);
            float4 v1 = *(const float4*)(asrc + k0 + 4);
            float4 v2 = *(const float4*)(asrc + k0 + 8);
            float4 v3 = *(const float4*)(asrc + k0 + 12);
            bf16x8 p0, p1;
            p0[0]=f2bf(v0.x); p0[1]=f2bf(v0.y); p0[2]=f2bf(v0.z); p0[3]=f2bf(v0.w);
            p0[4]=f2bf(v1.x); p0[5]=f2bf(v1.y); p0[6]=f2bf(v1.z); p0[7]=f2bf(v1.w);
            p1[0]=f2bf(v2.x); p1[1]=f2bf(v2.y); p1[2]=f2bf(v2.z); p1[3]=f2bf(v2.w);
            p1[4]=f2bf(v3.x); p1[5]=f2bf(v3.y); p1[6]=f2bf(v3.z); p1[7]=f2bf(v3.w);
            *(bf16x8*)&A_s[arow * 40 + ahalf * 16]     = p0;
            *(bf16x8*)&A_s[arow * 40 + ahalf * 16 + 8] = p1;
        }
        {   // stage B (already bf16)
            *(bf16x8*)&B_s[brow * 40 + bq * 8] =
                *(const bf16x8*)&WoaT[brow * 256 + k0 + bq * 8];
        }
        __syncthreads();
        bf16x8 af[4], bfv[2];
        const int kb = (l >> 4) * 8, r0 = wm * 64 + (l & 15), c0 = wn * 32 + (l & 15);
        #pragma unroll
        for (int am = 0; am < 4; ++am) af[am] = *(bf16x8*)&A_s[(r0 + am * 16) * 40 + kb];
        #pragma unroll
        for (int bn = 0; bn < 2; ++bn) bfv[bn] = *(bf16x8*)&B_s[(c0 + bn * 16) * 40 + kb];
        #pragma unroll
        for (int am = 0; am < 4; ++am)
            #pragma unroll
            for (int bn = 0; bn < 2; ++bn)
                acc[am][bn] = MFMA16(af[am], bfv[bn], acc[am][bn]);
        __syncthreads();
    }

    // epilogue: acc (+bias) -> olog (LDS union; A_s/B_s dead after last sync)
    #pragma unroll
    for (int bn = 0; bn < 2; ++bn) {
        const int col = wn * 32 + bn * 16 + (l & 15);
        const float bias = (col < 32) ? b_off[col] : b_attn[col - 32];
        #pragma unroll
        for (int am = 0; am < 4; ++am)
            #pragma unroll
            for (int j = 0; j < 4; ++j) {
                const int lr = wm * 64 + am * 16 + (l >> 4) * 4 + j;
                olog[lr * 65 + col] = acc[am][bn][j] + bias;
            }
    }
    __syncthreads();

    // softmax + temporal coefficients (threads 0..127, one query each)
    if (tid < 128) {
        const int q = q0 + tid;
        const int b = q / LQV;
        const int idx = idx_q[q];
        const float tr = t_ref_q[q];
        const float* ol = olog + tid * 65;
        int am = 0;
        #pragma unroll
        for (int h = 0; h < HH; ++h) {
            float off[KK], lg[KK];
            #pragma unroll
            for (int k = 0; k < KK; ++k) { off[k] = ol[h * 4 + k]; lg[k] = ol[32 + h * 4 + k]; }
            float m = fmaxf(fmaxf(lg[0], lg[1]), fmaxf(lg[2], lg[3]));
            float e[KK], s = 0.f;
            #pragma unroll
            for (int k = 0; k < KK; ++k) { e[k] = expf(lg[k] - m); s += e[k]; }
            const float inv = 1.f / s;
            float crow[TT] = {0.f,0.f,0.f,0.f,0.f,0.f,0.f,0.f};
            #pragma unroll
            for (int k = 0; k < KK; ++k) {
                const float w = e[k] * inv;
                float ts = fminf(fmaxf(tr + off[k], 0.f), (float)(TT - 1));
                const int t0 = (int)ts;
                const int t1 = min(t0 + 1, TT - 1);
                const float a = ts - (float)t0;
                const float w0 = w * (1.f - a), w1 = w * a;
                #pragma unroll
                for (int t = 0; t < TT; ++t)
                    crow[t] += ((t == t0) ? w0 : 0.f) + ((t == t1) ? w1 : 0.f);
                am |= (1 << t0) | (1 << t1);
            }
            float4 c0 = {crow[0], crow[1], crow[2], crow[3]};
            float4 c1 = {crow[4], crow[5], crow[6], crow[7]};
            *(float4*)&coefW[(size_t)q * 64 + h * 8]     = c0;
            *(float4*)&coefW[(size_t)q * 64 + h * 8 + 4] = c1;
        }
        amaskW[q] = am;
        const int base = b * (TT * LQV) + idx;
        #pragma unroll
        for (int t = 0; t < TT; ++t)
            if ((am >> t) & 1) flags[base + t * LQV] = 1;
    }
}

// ---------------------------------------------------------------------------
// K0d: compact flagged rows into list (unchanged, verified)
// ---------------------------------------------------------------------------
__global__ void k0d_compact(const int* __restrict__ flags, int* __restrict__ count,
                            int* __restrict__ list, int nrows)
{
    const int i = blockIdx.x * 256 + threadIdx.x;
    const bool p = (i < nrows) && (flags[i] != 0);
    const unsigned long long m = __ballot(p);
    const int lane = threadIdx.x & 63;
    const int lc = __popcll(m & ((1ull << lane) - 1ull));
    int base = 0;
    if (lane == 0) base = atomicAdd(count, __popcll(m));
    base = __shfl(base, 0);
    if (p) list[base + lc] = i;
}

// ---------------------------------------------------------------------------
// K1 v2 (r12): Z[rho][:] = Fp[rho][:] @ W_v over compacted rows.
//   Retiled BM 128 -> 64, 256 thr (4 waves; wave w owns n-tile w, wm=0 —
//   same verified fragment algebra as r11 with wm fixed to 0).
//   Rationale: r11's 512-thr blocks at ~650 active / 2-per-CU = 1.27
//   scheduling waves (2nd wave 27% full). 64-row blocks double the block
//   count, drop LDS 30->25KB, and let actual-VGPR (not the declared cap)
//   set occupancy.
// ---------------------------------------------------------------------------
__launch_bounds__(256, 2)
__global__ void k1_zgemm(const float* __restrict__ Fp, const unsigned short* __restrict__ WvT,
                         const int* __restrict__ count, const int* __restrict__ list,
                         unsigned short* __restrict__ Z)
{
    __shared__ __attribute__((aligned(16))) unsigned short A_s[64 * 40];   // 5 KB
    __shared__ __attribute__((aligned(16))) unsigned short B_s[256 * 40];  // 20 KB
    __shared__ int rows_s[64];
    const int cnt = count[0];
    const int bm0 = blockIdx.x * 64;
    if (bm0 >= cnt) return;
    const int tid = threadIdx.x;
    if (tid < 64) {
        const int i = bm0 + tid;
        rows_s[tid] = (i < cnt) ? list[i] : -1;
    }
    __syncthreads();
    const int w = tid >> 6, l = tid & 63;

    f32x4 acc[4][4];
    #pragma unroll
    for (int i = 0; i < 4; ++i)
        #pragma unroll
        for (int j = 0; j < 4; ++j) acc[i][j] = (f32x4){0.f, 0.f, 0.f, 0.f};

    const int arow = tid >> 2, aq = tid & 3;   // A stage: 64 rows, 8 f32 each
    int rho = rows_s[arow]; if (rho < 0) rho = 0;
    const float* asrc = Fp + (size_t)rho * CC + aq * 8;

    for (int ks = 0; ks < 8; ++ks) {
        const int k0 = ks * 32;
        {   // stage A (f32 -> bf16)
            float4 v0 = *(const float4*)(asrc + k0);
            float4 v1 = *(const float4*)(asrc + k0 + 4);
            bf16x8 p;
            p[0]=f2bf(v0.x); p[1]=f2bf(v0.y); p[2]=f2bf(v0.z); p[3]=f2bf(v0.w);
            p[4]=f2bf(v1.x); p[5]=f2bf(v1.y); p[6]=f2bf(v1.z); p[7]=f2bf(v1.w);
            *(bf16x8*)&A_s[arow * 40 + aq * 8] = p;
        }
        {   // stage B (bf16): one 32-elem K-slice of one WvT row per thread
            const bf16x8 q0 = *(const bf16x8*)&WvT[(size_t)tid * 256 + k0];
            const bf16x8 q1 = *(const bf16x8*)&WvT[(size_t)tid * 256 + k0 + 8];
            const bf16x8 q2 = *(const bf16x8*)&WvT[(size_t)tid * 256 + k0 + 16];
            const bf16x8 q3 = *(const bf16x8*)&WvT[(size_t)tid * 256 + k0 + 24];
            *(bf16x8*)&B_s[tid * 40 + 0]  = q0;
            *(bf16x8*)&B_s[tid * 40 + 8]  = q1;
            *(bf16x8*)&B_s[tid * 40 + 16] = q2;
            *(bf16x8*)&B_s[tid * 40 + 24] = q3;
        }
        __syncthreads();
        bf16x8 af[4], bfv[4];
        const int kb = (l >> 4) * 8, r0 = l & 15, c0 = w * 64 + (l & 15);
        #pragma unroll
        for (int am = 0; am < 4; ++am) af[am] = *(bf16x8*)&A_s[(r0 + am * 16) * 40 + kb];
        #pragma unroll
        for (int bn = 0; bn < 4; ++bn) bfv[bn] = *(bf16x8*)&B_s[(c0 + bn * 16) * 40 + kb];
        #pragma unroll
        for (int am = 0; am < 4; ++am)
            #pragma unroll
            for (int bn = 0; bn < 4; ++bn)
                acc[am][bn] = MFMA16(af[am], bfv[bn], acc[am][bn]);
        __syncthreads();
    }
    // C write (bf16, scattered rows)
    #pragma unroll
    for (int am = 0; am < 4; ++am) {
        #pragma unroll
        for (int j = 0; j < 4; ++j) {
            const int trow = am * 16 + (l >> 4) * 4 + j;
            const int r = rows_s[trow];
            if (r < 0) continue;
            #pragma unroll
            for (int bn = 0; bn < 4; ++bn) {
                const int col = w * 64 + bn * 16 + (l & 15);
                Z[(size_t)r * CC + col] = f2bf(acc[am][bn][j]);
            }
        }
    }
}

// ---------------------------------------------------------------------------
// K2: gather Z rows, combine with coef (+b_v), project with W_out (+b_out)
//   (byte-identical to r11, verified)
// ---------------------------------------------------------------------------
__launch_bounds__(256, 4)
__global__ void k2_final(const unsigned short* __restrict__ Z, const float* __restrict__ coefW,
                         const int* __restrict__ amaskW, const int* __restrict__ idx_q,
                         const unsigned short* __restrict__ WoutT,
                         const float* __restrict__ b_v, const float* __restrict__ b_out,
                         float* __restrict__ out)
{
    __shared__ float coef_s[16 * 68];                                    // 4.25 KB
    __shared__ __attribute__((aligned(16))) unsigned short ho_s[16 * 264]; // 8.25 KB
    __shared__ int am_s[16];
    __shared__ int base_s[16];
    const int tid = threadIdx.x;
    const int q0 = blockIdx.x * 16;

    if (tid < 128) {   // coef: 16 q x 64, float4-vectorized
        const int iq = tid >> 3, qd = tid & 7;
        const float4 v0 = *(const float4*)&coefW[(size_t)(q0 + iq) * 64 + qd * 8];
        const float4 v1 = *(const float4*)&coefW[(size_t)(q0 + iq) * 64 + qd * 8 + 4];
        *(float4*)&coef_s[iq * 68 + qd * 8]     = v0;
        *(float4*)&coef_s[iq * 68 + qd * 8 + 4] = v1;
    } else if (tid < 144) {
        const int i = tid - 128;
        const int q = q0 + i;
        am_s[i] = amaskW[q];
        base_s[i] = (q / LQV) * (TT * LQV) + idx_q[q];
    }
    __syncthreads();

    // gather-combine: 32 lanes span one Z row (16B/lane), thread owns 8 ch
    const int g = tid & 31;          // channel group: channels g*8 .. g*8+7
    const int iq0 = tid >> 5;        // 0..7
    const float4 bv0 = *(const float4*)&b_v[g * 8];
    const float4 bv1 = *(const float4*)&b_v[g * 8 + 4];
    #pragma unroll
    for (int p = 0; p < 2; ++p) {
        const int iq = iq0 + 8 * p;
        const int am = am_s[iq];
        const int base = base_s[iq];
        const float* cf = &coef_s[iq * 68 + (g >> 2) * 8];   // head = g/4
        float acc[8] = {bv0.x, bv0.y, bv0.z, bv0.w, bv1.x, bv1.y, bv1.z, bv1.w};
        #pragma unroll
        for (int t = 0; t < TT; ++t) {
            if ((am >> t) & 1) {
                const float c = cf[t];
                const uint4 zv = *(const uint4*)&Z[(size_t)(base + t * LQV) * CC + g * 8];
                acc[0] += c * bf2f((unsigned short)(zv.x & 0xffffu));
                acc[1] += c * bf2f((unsigned short)(zv.x >> 16));
                acc[2] += c * bf2f((unsigned short)(zv.y & 0xffffu));
                acc[3] += c * bf2f((unsigned short)(zv.y >> 16));
                acc[4] += c * bf2f((unsigned short)(zv.z & 0xffffu));
                acc[5] += c * bf2f((unsigned short)(zv.z >> 16));
                acc[6] += c * bf2f((unsigned short)(zv.w & 0xffffu));
                acc[7] += c * bf2f((unsigned short)(zv.w >> 16));
            }
        }
        bf16x8 hp;
        #pragma unroll
        for (int j = 0; j < 8; ++j) hp[j] = (short)f2bf(acc[j]);
        *(bf16x8*)&ho_s[iq * 264 + g * 8] = hp;
    }
    __syncthreads();

    // out = HO @ W_out + b_out ; wave w owns n-tiles [w*4, w*4+4)
    const int wid = tid >> 6, l = tid & 63;
    const int kb = (l >> 4) * 8, r = l & 15;
    f32x4 acc[4];
    #pragma unroll
    for (int nt = 0; nt < 4; ++nt) acc[nt] = (f32x4){0.f, 0.f, 0.f, 0.f};
    for (int ks = 0; ks < 8; ++ks) {
        const bf16x8 a = *(bf16x8*)&ho_s[r * 264 + ks * 32 + kb];
        #pragma unroll
        for (int nt = 0; nt < 4; ++nt) {
            const int col = (wid * 4 + nt) * 16 + r;
            const bf16x8 bfr = *(const bf16x8*)&WoutT[(size_t)col * 256 + ks * 32 + kb];
            acc[nt] = MFMA16(a, bfr, acc[nt]);
        }
    }
    #pragma unroll
    for (int nt = 0; nt < 4; ++nt) {
        const int col = (wid * 4 + nt) * 16 + r;
        const float bo = b_out[col];
        #pragma unroll
        for (int j = 0; j < 4; ++j) {
            const int row = (l >> 4) * 4 + j;
            out[(size_t)(q0 + row) * CC + col] = acc[nt][j] + bo;
        }
    }
}

// ---------------------------------------------------------------------------
// Fallback: round-1 fused VALU kernel (used if ws is too small)
// ---------------------------------------------------------------------------
#define QB 8
__launch_bounds__(256, 2)
__global__ void tda_fused(const float* __restrict__ Fp, const float* __restrict__ queries,
                          const int* __restrict__ idx_q, const float* __restrict__ t_ref_q,
                          const float* __restrict__ W_off, const float* __restrict__ b_off,
                          const float* __restrict__ W_attn, const float* __restrict__ b_attn,
                          const float* __restrict__ W_v, const float* __restrict__ b_v,
                          const float* __restrict__ W_out, const float* __restrict__ b_out,
                          float* __restrict__ out, int Lv)
{
    __shared__ __attribute__((aligned(16))) float g_s[QB][HH][CC];
    __shared__ __attribute__((aligned(16))) float qho_s[QB][CC];
    __shared__ float offlog[QB][64];
    __shared__ float coef[QB][HH][TT];
    __shared__ float tref_s[QB];
    __shared__ int idx_s[QB];
    __shared__ int amask[QB];
    const int tid = threadIdx.x;
    const long qbase = (long)blockIdx.x * QB;
    const int b = (int)(qbase / LQV);
    #pragma unroll
    for (int i = 0; i < QB; ++i) qho_s[i][tid] = queries[(qbase + i) * CC + tid];
    if (tid < QB) { tref_s[tid] = t_ref_q[qbase + tid]; idx_s[tid] = idx_q[qbase + tid]; amask[tid] = 0; }
    { float* cfp = &coef[0][0][0]; cfp[tid] = 0.f; cfp[tid + 256] = 0.f; }
    __syncthreads();
    {
        const int o = tid & 63, i0 = tid >> 6, col = o & 31;
        const float* W = (o < 32) ? W_off : W_attn;
        const float bias = (o < 32) ? b_off[col] : b_attn[col];
        float acc0 = 0.f, acc1 = 0.f;
        for (int c = 0; c < CC; ++c) {
            const float w = W[c * 32 + col];
            acc0 += qho_s[i0][c] * w; acc1 += qho_s[i0 + 4][c] * w;
        }
        offlog[i0][o] = acc0 + bias; offlog[i0 + 4][o] = acc1 + bias;
    }
    __syncthreads();
    if (tid < QB * HH) {
        const int i = tid >> 3, h = tid & 7;
        float off[KK], lg[KK];
        #pragma unroll
        for (int k = 0; k < KK; ++k) { off[k] = offlog[i][h * KK + k]; lg[k] = offlog[i][32 + h * KK + k]; }
        float m = fmaxf(fmaxf(lg[0], lg[1]), fmaxf(lg[2], lg[3]));
        float e[KK], s = 0.f;
        #pragma unroll
        for (int k = 0; k < KK; ++k) { e[k] = expf(lg[k] - m); s += e[k]; }
        const float inv = 1.f / s;
        const float tr = tref_s[i];
        int mask = 0;
        #pragma unroll
        for (int k = 0; k < KK; ++k) {
            const float w = e[k] * inv;
            float ts = fminf(fmaxf(tr + off[k], 0.f), (float)(TT - 1));
            const int t0 = (int)ts; const int t1 = min(t0 + 1, TT - 1);
            const float a = ts - (float)t0;
            coef[i][h][t0] += w * (1.f - a); coef[i][h][t1] += w * a;
            mask |= (1 << t0) | (1 << t1);
        }
        atomicOr(&amask[i], mask);
    }
    __syncthreads();
    for (int i = 0; i < QB; ++i) {
        float g[HH] = {0.f,0.f,0.f,0.f,0.f,0.f,0.f,0.f};
        const int am = amask[i]; const int idx = idx_s[i];
        for (int t = 0; t < TT; ++t) {
            if ((am >> t) & 1) {
                const float rv = Fp[((long)(b * TT + t) * Lv + idx) * CC + tid];
                #pragma unroll
                for (int h = 0; h < HH; ++h) g[h] += coef[i][h][t] * rv;
            }
        }
        #pragma unroll
        for (int h = 0; h < HH; ++h) g_s[i][h][tid] = g[h];
    }
    __syncthreads();
    {
        const int h = tid >> 5;
        float acc[QB];
        #pragma unroll
        for (int i = 0; i < QB; ++i) acc[i] = b_v[tid];
        for (int c = 0; c < CC; c += 4) {
            const float w0 = W_v[(c + 0) * CC + tid], w1 = W_v[(c + 1) * CC + tid];
            const float w2 = W_v[(c + 2) * CC + tid], w3 = W_v[(c + 3) * CC + tid];
            #pragma unroll
            for (int i = 0; i < QB; ++i) {
                const float4 gv = *reinterpret_cast<const float4*>(&g_s[i][h][c]);
                acc[i] += gv.x * w0 + gv.y * w1 + gv.z * w2 + gv.w * w3;
            }
        }
        __syncthreads();
        #pragma unroll
        for (int i = 0; i < QB; ++i) qho_s[i][tid] = acc[i];
    }
    __syncthreads();
    {
        float acc[QB];
        #pragma unroll
        for (int i = 0; i < QB; ++i) acc[i] = b_out[tid];
        for (int c = 0; c < CC; c += 4) {
            const float w0 = W_out[(c + 0) * CC + tid], w1 = W_out[(c + 1) * CC + tid];
            const float w2 = W_out[(c + 2) * CC + tid], w3 = W_out[(c + 3) * CC + tid];
            #pragma unroll
            for (int i = 0; i < QB; ++i) {
                const float4 hv = *reinterpret_cast<const float4*>(&qho_s[i][c]);
                acc[i] += hv.x * w0 + hv.y * w1 + hv.z * w2 + hv.w * w3;
            }
        }
        #pragma unroll
        for (int i = 0; i < QB; ++i) out[(qbase + i) * CC + tid] = acc[i];
    }
}

// ---------------------------------------------------------------------------
extern "C" void kernel_launch(void* const* d_in, const int* in_sizes, int n_in,
                              void* d_out, int out_size, void* d_ws, size_t ws_size,
                              hipStream_t stream) {
    const float* Fp      = (const float*)d_in[0];
    const float* queries = (const float*)d_in[1];
    const int*   idx_q   = (const int*)d_in[2];
    const float* t_ref   = (const float*)d_in[3];
    const float* W_off   = (const float*)d_in[4];
    const float* b_off   = (const float*)d_in[5];
    const float* W_attn  = (const float*)d_in[6];
    const float* b_attn  = (const float*)d_in[7];
    const float* W_v     = (const float*)d_in[8];
    const float* b_v     = (const float*)d_in[9];
    const float* W_out   = (const float*)d_in[10];
    const float* b_out   = (const float*)d_in[11];
    float* out = (float*)d_out;

    const int nq    = in_sizes[2];            // B * Lq = 36864
    const int Bdim  = nq / LQV;               // 4
    const int nrows = Bdim * TT * LQV;        // 294912

    // workspace layout (flags+count adjacent -> single zeroing memset)
    size_t cur = 0;
    auto alloc = [&](size_t bytes) { size_t o = cur; cur += (bytes + 255) & ~(size_t)255; return o; };
    const size_t o_Z      = alloc((size_t)nrows * CC * 2);       // bf16 Z
    const size_t o_coef   = alloc((size_t)nq * 64 * 4);
    const size_t o_amask  = alloc((size_t)nq * 4);
    const size_t o_flags  = alloc((size_t)nrows * 4);            // nrows*4 is 256-mult
    const size_t o_count  = alloc(256);                          // adjacent to flags
    const size_t o_list   = alloc((size_t)nrows * 4);
    const size_t o_WvT    = alloc(65536 * 2);
    const size_t o_WoutT  = alloc(65536 * 2);
    const size_t o_WoaT   = alloc(16384 * 2);
    const size_t need = cur;

    if (ws_size < need) {
        tda_fused<<<nq / QB, 256, 0, stream>>>(Fp, queries, idx_q, t_ref,
                                               W_off, b_off, W_attn, b_attn,
                                               W_v, b_v, W_out, b_out, out, LQV);
        return;
    }

    char* ws = (char*)d_ws;
    unsigned short* Z     = (unsigned short*)(ws + o_Z);
    float* coefW          = (float*)(ws + o_coef);
    int*   amaskW         = (int*)(ws + o_amask);
    int*   flags          = (int*)(ws + o_flags);
    int*   count          = (int*)(ws + o_count);
    int*   list           = (int*)(ws + o_list);
    unsigned short* WvT   = (unsigned short*)(ws + o_WvT);
    unsigned short* WoutT = (unsigned short*)(ws + o_WoutT);
    unsigned short* WoaT  = (unsigned short*)(ws + o_WoaT);

    // zero flags + count in ONE async memset (they are adjacent)
    hipMemsetAsync(flags, 0, (size_t)nrows * 4 + 256, stream);

    k0_prep<<<576, 256, 0, stream>>>(W_v, W_out, W_off, W_attn, WvT, WoutT, WoaT);
    k1b_offcoef<<<nq / 128, 256, 0, stream>>>(queries, WoaT, b_off, b_attn,
                                              idx_q, t_ref, coefW, amaskW, flags);
    k0d_compact<<<(nrows + 255) / 256, 256, 0, stream>>>(flags, count, list, nrows);
    k1_zgemm<<<(nrows + 63) / 64, 256, 0, stream>>>(Fp, WvT, count, list, Z);
    k2_final<<<nq / 16, 256, 0, stream>>>(Z, coefW, amaskW, idx_q, WoutT,
                                          b_v, b_out, out);
}

// Round 13
// 195.194 us; speedup vs baseline: 1.0280x; 1.0280x over previous
//
#include <hip/hip_runtime.h>
#include <hip/hip_bf16.h>

#define HH 8
#define KK 4
#define CC 256
#define TT 8
#define LQV 9216        // Lq == Lv (fixed problem shape)

typedef __attribute__((ext_vector_type(8))) short bf16x8;
typedef __attribute__((ext_vector_type(4))) float f32x4;

#define MFMA16(a, b, c) __builtin_amdgcn_mfma_f32_16x16x32_bf16(a, b, c, 0, 0, 0)

__device__ __forceinline__ unsigned short f2bf(float f) {
    union { float f; unsigned u; } v; v.f = f;
    unsigned r = v.u + 0x7fffu + ((v.u >> 16) & 1u);
    return (unsigned short)(r >> 16);
}
__device__ __forceinline__ float bf2f(unsigned short s) {
    union { unsigned u; float f; } v; v.u = ((unsigned)s) << 16;
    return v.f;
}

// ---------------------------------------------------------------------------
// K0: build bf16-transposed weights (verified r2-r12)
// ---------------------------------------------------------------------------
__global__ void k0_prep(const float* __restrict__ Wv, const float* __restrict__ Wout,
                        const float* __restrict__ Woff, const float* __restrict__ Wattn,
                        unsigned short* __restrict__ WvT, unsigned short* __restrict__ WoutT,
                        unsigned short* __restrict__ WoaT)
{
    int o = blockIdx.x * 256 + threadIdx.x;
    if (o < 65536) { int d = o >> 8, c = o & 255; WvT[o]   = f2bf(Wv[c * 256 + d]);   return; }
    o -= 65536;
    if (o < 65536) { int d = o >> 8, c = o & 255; WoutT[o] = f2bf(Wout[c * 256 + d]); return; }
    o -= 65536;
    if (o < 16384) {
        int n = o >> 8, c = o & 255;
        WoaT[o] = f2bf(n < 32 ? Woff[c * 32 + n] : Wattn[c * 32 + (n - 32)]);
    }
}

// ---------------------------------------------------------------------------
// K1b: offsets/logits GEMM fused with softmax -> coef/amask/flags
//   (byte-identical to r11, verified)
// ---------------------------------------------------------------------------
__launch_bounds__(256, 2)
__global__ void k1b_offcoef(const float* __restrict__ queries, const unsigned short* __restrict__ WoaT,
                            const float* __restrict__ b_off, const float* __restrict__ b_attn,
                            const int* __restrict__ idx_q, const float* __restrict__ t_ref_q,
                            float* __restrict__ coefW, int* __restrict__ amaskW,
                            int* __restrict__ flags)
{
    __shared__ __attribute__((aligned(16))) char smem[128 * 65 * 4];   // 33.3 KB union
    unsigned short* A_s = (unsigned short*)smem;                 // [128][40]
    unsigned short* B_s = (unsigned short*)(smem + 128 * 40 * 2); // [64][40]
    float* olog = (float*)smem;                                  // [128][65]

    const int tid = threadIdx.x;
    const int q0 = blockIdx.x * 128;
    const int wid = tid >> 6, l = tid & 63;
    const int wm = wid >> 1, wn = wid & 1;

    f32x4 acc[4][2];
    #pragma unroll
    for (int i = 0; i < 4; ++i)
        #pragma unroll
        for (int j = 0; j < 2; ++j) acc[i][j] = (f32x4){0.f, 0.f, 0.f, 0.f};

    const int arow = tid >> 1, ahalf = tid & 1;      // A stage: 16 f32 each
    const int brow = tid >> 2, bq = tid & 3;         // B stage: 8 bf16 each
    const float* asrc = queries + (size_t)(q0 + arow) * CC + ahalf * 16;

    for (int ks = 0; ks < 8; ++ks) {
        const int k0 = ks * 32;
        {   // stage A (f32 -> bf16)
            float4 v0 = *(const float4*)(asrc + k0);
            float4 v1 = *(const float4*)(asrc + k0 + 4);
            float4 v2 = *(const float4*)(asrc + k0 + 8);
            float4 v3 = *(const float4*)(asrc + k0 + 12);
            bf16x8 p0, p1;
            p0[0]=f2bf(v0.x); p0[1]=f2bf(v0.y); p0[2]=f2bf(v0.z); p0[3]=f2bf(v0.w);
            p0[4]=f2bf(v1.x); p0[5]=f2bf(v1.y); p0[6]=f2bf(v1.z); p0[7]=f2bf(v1.w);
            p1[0]=f2bf(v2.x); p1[1]=f2bf(v2.y); p1[2]=f2bf(v2.z); p1[3]=f2bf(v2.w);
            p1[4]=f2bf(v3.x); p1[5]=f2bf(v3.y); p1[6]=f2bf(v3.z); p1[7]=f2bf(v3.w);
            *(bf16x8*)&A_s[arow * 40 + ahalf * 16]     = p0;
            *(bf16x8*)&A_s[arow * 40 + ahalf * 16 + 8] = p1;
        }
        {   // stage B (already bf16)
            *(bf16x8*)&B_s[brow * 40 + bq * 8] =
                *(const bf16x8*)&WoaT[brow * 256 + k0 + bq * 8];
        }
        __syncthreads();
        bf16x8 af[4], bfv[2];
        const int kb = (l >> 4) * 8, r0 = wm * 64 + (l & 15), c0 = wn * 32 + (l & 15);
        #pragma unroll
        for (int am = 0; am < 4; ++am) af[am] = *(bf16x8*)&A_s[(r0 + am * 16) * 40 + kb];
        #pragma unroll
        for (int bn = 0; bn < 2; ++bn) bfv[bn] = *(bf16x8*)&B_s[(c0 + bn * 16) * 40 + kb];
        #pragma unroll
        for (int am = 0; am < 4; ++am)
            #pragma unroll
            for (int bn = 0; bn < 2; ++bn)
                acc[am][bn] = MFMA16(af[am], bfv[bn], acc[am][bn]);
        __syncthreads();
    }

    // epilogue: acc (+bias) -> olog (LDS union; A_s/B_s dead after last sync)
    #pragma unroll
    for (int bn = 0; bn < 2; ++bn) {
        const int col = wn * 32 + bn * 16 + (l & 15);
        const float bias = (col < 32) ? b_off[col] : b_attn[col - 32];
        #pragma unroll
        for (int am = 0; am < 4; ++am)
            #pragma unroll
            for (int j = 0; j < 4; ++j) {
                const int lr = wm * 64 + am * 16 + (l >> 4) * 4 + j;
                olog[lr * 65 + col] = acc[am][bn][j] + bias;
            }
    }
    __syncthreads();

    // softmax + temporal coefficients (threads 0..127, one query each)
    if (tid < 128) {
        const int q = q0 + tid;
        const int b = q / LQV;
        const int idx = idx_q[q];
        const float tr = t_ref_q[q];
        const float* ol = olog + tid * 65;
        int am = 0;
        #pragma unroll
        for (int h = 0; h < HH; ++h) {
            float off[KK], lg[KK];
            #pragma unroll
            for (int k = 0; k < KK; ++k) { off[k] = ol[h * 4 + k]; lg[k] = ol[32 + h * 4 + k]; }
            float m = fmaxf(fmaxf(lg[0], lg[1]), fmaxf(lg[2], lg[3]));
            float e[KK], s = 0.f;
            #pragma unroll
            for (int k = 0; k < KK; ++k) { e[k] = expf(lg[k] - m); s += e[k]; }
            const float inv = 1.f / s;
            float crow[TT] = {0.f,0.f,0.f,0.f,0.f,0.f,0.f,0.f};
            #pragma unroll
            for (int k = 0; k < KK; ++k) {
                const float w = e[k] * inv;
                float ts = fminf(fmaxf(tr + off[k], 0.f), (float)(TT - 1));
                const int t0 = (int)ts;
                const int t1 = min(t0 + 1, TT - 1);
                const float a = ts - (float)t0;
                const float w0 = w * (1.f - a), w1 = w * a;
                #pragma unroll
                for (int t = 0; t < TT; ++t)
                    crow[t] += ((t == t0) ? w0 : 0.f) + ((t == t1) ? w1 : 0.f);
                am |= (1 << t0) | (1 << t1);
            }
            float4 c0 = {crow[0], crow[1], crow[2], crow[3]};
            float4 c1 = {crow[4], crow[5], crow[6], crow[7]};
            *(float4*)&coefW[(size_t)q * 64 + h * 8]     = c0;
            *(float4*)&coefW[(size_t)q * 64 + h * 8 + 4] = c1;
        }
        amaskW[q] = am;
        const int base = b * (TT * LQV) + idx;
        #pragma unroll
        for (int t = 0; t < TT; ++t)
            if ((am >> t) & 1) flags[base + t * LQV] = 1;
    }
}

// ---------------------------------------------------------------------------
// K0d: compact flagged rows into list (unchanged, verified)
// ---------------------------------------------------------------------------
__global__ void k0d_compact(const int* __restrict__ flags, int* __restrict__ count,
                            int* __restrict__ list, int nrows)
{
    const int i = blockIdx.x * 256 + threadIdx.x;
    const bool p = (i < nrows) && (flags[i] != 0);
    const unsigned long long m = __ballot(p);
    const int lane = threadIdx.x & 63;
    const int lc = __popcll(m & ((1ull << lane) - 1ull));
    int base = 0;
    if (lane == 0) base = atomicAdd(count, __popcll(m));
    base = __shfl(base, 0);
    if (p) list[base + lc] = i;
}

// ---------------------------------------------------------------------------
// K1 v3 (r13): r11 shape (BM=128, 512 thr) with B_s staging REMOVED —
//   B-fragments read directly from WvT (128 KB, fully L2-resident), the
//   pattern verified in r7-kC. A staging byte-identical to r11.
//   r12 lesson: k1 is staging-amortization-bound; this removes half the
//   staged bytes and LDS drops 30 -> 10 KB.
// ---------------------------------------------------------------------------
__launch_bounds__(512, 2)
__global__ void k1_zgemm(const float* __restrict__ Fp, const unsigned short* __restrict__ WvT,
                         const int* __restrict__ count, const int* __restrict__ list,
                         unsigned short* __restrict__ Z)
{
    __shared__ __attribute__((aligned(16))) unsigned short A_s[128 * 40];  // 10 KB
    __shared__ int rows_s[128];
    const int cnt = count[0];
    const int bm0 = blockIdx.x * 128;
    if (bm0 >= cnt) return;
    const int tid = threadIdx.x;
    if (tid < 128) {
        const int i = bm0 + tid;
        rows_s[tid] = (i < cnt) ? list[i] : -1;
    }
    __syncthreads();
    const int wid = tid >> 6, l = tid & 63;
    const int wm = wid >> 2, wn = wid & 3;

    f32x4 acc[4][4];
    #pragma unroll
    for (int i = 0; i < 4; ++i)
        #pragma unroll
        for (int j = 0; j < 4; ++j) acc[i][j] = (f32x4){0.f, 0.f, 0.f, 0.f};

    const int arow = tid >> 2, aq = tid & 3;   // A stage: 8 f32 each
    int rho = rows_s[arow]; if (rho < 0) rho = 0;
    const float* asrc = Fp + (size_t)rho * CC + aq * 8;

    for (int ks = 0; ks < 8; ++ks) {
        const int k0 = ks * 32;
        {   // stage A (f32 -> bf16) — identical to r11
            float4 v0 = *(const float4*)(asrc + k0);
            float4 v1 = *(const float4*)(asrc + k0 + 4);
            bf16x8 p;
            p[0]=f2bf(v0.x); p[1]=f2bf(v0.y); p[2]=f2bf(v0.z); p[3]=f2bf(v0.w);
            p[4]=f2bf(v1.x); p[5]=f2bf(v1.y); p[6]=f2bf(v1.z); p[7]=f2bf(v1.w);
            *(bf16x8*)&A_s[arow * 40 + aq * 8] = p;
        }
        __syncthreads();
        bf16x8 af[4], bfv[4];
        const int kb = (l >> 4) * 8, r0 = wm * 64 + (l & 15), c0 = wn * 64 + (l & 15);
        #pragma unroll
        for (int am = 0; am < 4; ++am) af[am] = *(bf16x8*)&A_s[(r0 + am * 16) * 40 + kb];
        #pragma unroll
        for (int bn = 0; bn < 4; ++bn)   // direct from L2-resident WvT (r7-kC pattern)
            bfv[bn] = *(const bf16x8*)&WvT[(size_t)(c0 + bn * 16) * 256 + k0 + kb];
        #pragma unroll
        for (int am = 0; am < 4; ++am)
            #pragma unroll
            for (int bn = 0; bn < 4; ++bn)
                acc[am][bn] = MFMA16(af[am], bfv[bn], acc[am][bn]);
        __syncthreads();
    }
    // C write (bf16, scattered rows) — identical to r11
    #pragma unroll
    for (int am = 0; am < 4; ++am) {
        #pragma unroll
        for (int j = 0; j < 4; ++j) {
            const int trow = wm * 64 + am * 16 + (l >> 4) * 4 + j;
            const int r = rows_s[trow];
            if (r < 0) continue;
            #pragma unroll
            for (int bn = 0; bn < 4; ++bn) {
                const int col = wn * 64 + bn * 16 + (l & 15);
                Z[(size_t)r * CC + col] = f2bf(acc[am][bn][j]);
            }
        }
    }
}

// ---------------------------------------------------------------------------
// K2: gather Z rows, combine with coef (+b_v), project with W_out (+b_out)
//   (byte-identical to r11, verified)
// ---------------------------------------------------------------------------
__launch_bounds__(256, 4)
__global__ void k2_final(const unsigned short* __restrict__ Z, const float* __restrict__ coefW,
                         const int* __restrict__ amaskW, const int* __restrict__ idx_q,
                         const unsigned short* __restrict__ WoutT,
                         const float* __restrict__ b_v, const float* __restrict__ b_out,
                         float* __restrict__ out)
{
    __shared__ float coef_s[16 * 68];                                    // 4.25 KB
    __shared__ __attribute__((aligned(16))) unsigned short ho_s[16 * 264]; // 8.25 KB
    __shared__ int am_s[16];
    __shared__ int base_s[16];
    const int tid = threadIdx.x;
    const int q0 = blockIdx.x * 16;

    if (tid < 128) {   // coef: 16 q x 64, float4-vectorized
        const int iq = tid >> 3, qd = tid & 7;
        const float4 v0 = *(const float4*)&coefW[(size_t)(q0 + iq) * 64 + qd * 8];
        const float4 v1 = *(const float4*)&coefW[(size_t)(q0 + iq) * 64 + qd * 8 + 4];
        *(float4*)&coef_s[iq * 68 + qd * 8]     = v0;
        *(float4*)&coef_s[iq * 68 + qd * 8 + 4] = v1;
    } else if (tid < 144) {
        const int i = tid - 128;
        const int q = q0 + i;
        am_s[i] = amaskW[q];
        base_s[i] = (q / LQV) * (TT * LQV) + idx_q[q];
    }
    __syncthreads();

    // gather-combine: 32 lanes span one Z row (16B/lane), thread owns 8 ch
    const int g = tid & 31;          // channel group: channels g*8 .. g*8+7
    const int iq0 = tid >> 5;        // 0..7
    const float4 bv0 = *(const float4*)&b_v[g * 8];
    const float4 bv1 = *(const float4*)&b_v[g * 8 + 4];
    #pragma unroll
    for (int p = 0; p < 2; ++p) {
        const int iq = iq0 + 8 * p;
        const int am = am_s[iq];
        const int base = base_s[iq];
        const float* cf = &coef_s[iq * 68 + (g >> 2) * 8];   // head = g/4
        float acc[8] = {bv0.x, bv0.y, bv0.z, bv0.w, bv1.x, bv1.y, bv1.z, bv1.w};
        #pragma unroll
        for (int t = 0; t < TT; ++t) {
            if ((am >> t) & 1) {
                const float c = cf[t];
                const uint4 zv = *(const uint4*)&Z[(size_t)(base + t * LQV) * CC + g * 8];
                acc[0] += c * bf2f((unsigned short)(zv.x & 0xffffu));
                acc[1] += c * bf2f((unsigned short)(zv.x >> 16));
                acc[2] += c * bf2f((unsigned short)(zv.y & 0xffffu));
                acc[3] += c * bf2f((unsigned short)(zv.y >> 16));
                acc[4] += c * bf2f((unsigned short)(zv.z & 0xffffu));
                acc[5] += c * bf2f((unsigned short)(zv.z >> 16));
                acc[6] += c * bf2f((unsigned short)(zv.w & 0xffffu));
                acc[7] += c * bf2f((unsigned short)(zv.w >> 16));
            }
        }
        bf16x8 hp;
        #pragma unroll
        for (int j = 0; j < 8; ++j) hp[j] = (short)f2bf(acc[j]);
        *(bf16x8*)&ho_s[iq * 264 + g * 8] = hp;
    }
    __syncthreads();

    // out = HO @ W_out + b_out ; wave w owns n-tiles [w*4, w*4+4)
    const int wid = tid >> 6, l = tid & 63;
    const int kb = (l >> 4) * 8, r = l & 15;
    f32x4 acc[4];
    #pragma unroll
    for (int nt = 0; nt < 4; ++nt) acc[nt] = (f32x4){0.f, 0.f, 0.f, 0.f};
    for (int ks = 0; ks < 8; ++ks) {
        const bf16x8 a = *(bf16x8*)&ho_s[r * 264 + ks * 32 + kb];
        #pragma unroll
        for (int nt = 0; nt < 4; ++nt) {
            const int col = (wid * 4 + nt) * 16 + r;
            const bf16x8 bfr = *(const bf16x8*)&WoutT[(size_t)col * 256 + ks * 32 + kb];
            acc[nt] = MFMA16(a, bfr, acc[nt]);
        }
    }
    #pragma unroll
    for (int nt = 0; nt < 4; ++nt) {
        const int col = (wid * 4 + nt) * 16 + r;
        const float bo = b_out[col];
        #pragma unroll
        for (int j = 0; j < 4; ++j) {
            const int row = (l >> 4) * 4 + j;
            out[(size_t)(q0 + row) * CC + col] = acc[nt][j] + bo;
        }
    }
}

// ---------------------------------------------------------------------------
// Fallback: round-1 fused VALU kernel (used if ws is too small)
// ---------------------------------------------------------------------------
#define QB 8
__launch_bounds__(256, 2)
__global__ void tda_fused(const float* __restrict__ Fp, const float* __restrict__ queries,
                          const int* __restrict__ idx_q, const float* __restrict__ t_ref_q,
                          const float* __restrict__ W_off, const float* __restrict__ b_off,
                          const float* __restrict__ W_attn, const float* __restrict__ b_attn,
                          const float* __restrict__ W_v, const float* __restrict__ b_v,
                          const float* __restrict__ W_out, const float* __restrict__ b_out,
                          float* __restrict__ out, int Lv)
{
    __shared__ __attribute__((aligned(16))) float g_s[QB][HH][CC];
    __shared__ __attribute__((aligned(16))) float qho_s[QB][CC];
    __shared__ float offlog[QB][64];
    __shared__ float coef[QB][HH][TT];
    __shared__ float tref_s[QB];
    __shared__ int idx_s[QB];
    __shared__ int amask[QB];
    const int tid = threadIdx.x;
    const long qbase = (long)blockIdx.x * QB;
    const int b = (int)(qbase / LQV);
    #pragma unroll
    for (int i = 0; i < QB; ++i) qho_s[i][tid] = queries[(qbase + i) * CC + tid];
    if (tid < QB) { tref_s[tid] = t_ref_q[qbase + tid]; idx_s[tid] = idx_q[qbase + tid]; amask[tid] = 0; }
    { float* cfp = &coef[0][0][0]; cfp[tid] = 0.f; cfp[tid + 256] = 0.f; }
    __syncthreads();
    {
        const int o = tid & 63, i0 = tid >> 6, col = o & 31;
        const float* W = (o < 32) ? W_off : W_attn;
        const float bias = (o < 32) ? b_off[col] : b_attn[col];
        float acc0 = 0.f, acc1 = 0.f;
        for (int c = 0; c < CC; ++c) {
            const float w = W[c * 32 + col];
            acc0 += qho_s[i0][c] * w; acc1 += qho_s[i0 + 4][c] * w;
        }
        offlog[i0][o] = acc0 + bias; offlog[i0 + 4][o] = acc1 + bias;
    }
    __syncthreads();
    if (tid < QB * HH) {
        const int i = tid >> 3, h = tid & 7;
        float off[KK], lg[KK];
        #pragma unroll
        for (int k = 0; k < KK; ++k) { off[k] = offlog[i][h * KK + k]; lg[k] = offlog[i][32 + h * KK + k]; }
        float m = fmaxf(fmaxf(lg[0], lg[1]), fmaxf(lg[2], lg[3]));
        float e[KK], s = 0.f;
        #pragma unroll
        for (int k = 0; k < KK; ++k) { e[k] = expf(lg[k] - m); s += e[k]; }
        const float inv = 1.f / s;
        const float tr = tref_s[i];
        int mask = 0;
        #pragma unroll
        for (int k = 0; k < KK; ++k) {
            const float w = e[k] * inv;
            float ts = fminf(fmaxf(tr + off[k], 0.f), (float)(TT - 1));
            const int t0 = (int)ts; const int t1 = min(t0 + 1, TT - 1);
            const float a = ts - (float)t0;
            coef[i][h][t0] += w * (1.f - a); coef[i][h][t1] += w * a;
            mask |= (1 << t0) | (1 << t1);
        }
        atomicOr(&amask[i], mask);
    }
    __syncthreads();
    for (int i = 0; i < QB; ++i) {
        float g[HH] = {0.f,0.f,0.f,0.f,0.f,0.f,0.f,0.f};
        const int am = amask[i]; const int idx = idx_s[i];
        for (int t = 0; t < TT; ++t) {
            if ((am >> t) & 1) {
                const float rv = Fp[((long)(b * TT + t) * Lv + idx) * CC + tid];
                #pragma unroll
                for (int h = 0; h < HH; ++h) g[h] += coef[i][h][t] * rv;
            }
        }
        #pragma unroll
        for (int h = 0; h < HH; ++h) g_s[i][h][tid] = g[h];
    }
    __syncthreads();
    {
        const int h = tid >> 5;
        float acc[QB];
        #pragma unroll
        for (int i = 0; i < QB; ++i) acc[i] = b_v[tid];
        for (int c = 0; c < CC; c += 4) {
            const float w0 = W_v[(c + 0) * CC + tid], w1 = W_v[(c + 1) * CC + tid];
            const float w2 = W_v[(c + 2) * CC + tid], w3 = W_v[(c + 3) * CC + tid];
            #pragma unroll
            for (int i = 0; i < QB; ++i) {
                const float4 gv = *reinterpret_cast<const float4*>(&g_s[i][h][c]);
                acc[i] += gv.x * w0 + gv.y * w1 + gv.z * w2 + gv.w * w3;
            }
        }
        __syncthreads();
        #pragma unroll
        for (int i = 0; i < QB; ++i) qho_s[i][tid] = acc[i];
    }
    __syncthreads();
    {
        float acc[QB];
        #pragma unroll
        for (int i = 0; i < QB; ++i) acc[i] = b_out[tid];
        for (int c = 0; c < CC; c += 4) {
            const float w0 = W_out[(c + 0) * CC + tid], w1 = W_out[(c + 1) * CC + tid];
            const float w2 = W_out[(c + 2) * CC + tid], w3 = W_out[(c + 3) * CC + tid];
            #pragma unroll
            for (int i = 0; i < QB; ++i) {
                const float4 hv = *reinterpret_cast<const float4*>(&qho_s[i][c]);
                acc[i] += hv.x * w0 + hv.y * w1 + hv.z * w2 + hv.w * w3;
            }
        }
        #pragma unroll
        for (int i = 0; i < QB; ++i) out[(qbase + i) * CC + tid] = acc[i];
    }
}

// ---------------------------------------------------------------------------
extern "C" void kernel_launch(void* const* d_in, const int* in_sizes, int n_in,
                              void* d_out, int out_size, void* d_ws, size_t ws_size,
                              hipStream_t stream) {
    const float* Fp      = (const float*)d_in[0];
    const float* queries = (const float*)d_in[1];
    const int*   idx_q   = (const int*)d_in[2];
    const float* t_ref   = (const float*)d_in[3];
    const float* W_off   = (const float*)d_in[4];
    const float* b_off   = (const float*)d_in[5];
    const float* W_attn  = (const float*)d_in[6];
    const float* b_attn  = (const float*)d_in[7];
    const float* W_v     = (const float*)d_in[8];
    const float* b_v     = (const float*)d_in[9];
    const float* W_out   = (const float*)d_in[10];
    const float* b_out   = (const float*)d_in[11];
    float* out = (float*)d_out;

    const int nq    = in_sizes[2];            // B * Lq = 36864
    const int Bdim  = nq / LQV;               // 4
    const int nrows = Bdim * TT * LQV;        // 294912

    // workspace layout (flags+count adjacent -> single zeroing memset)
    size_t cur = 0;
    auto alloc = [&](size_t bytes) { size_t o = cur; cur += (bytes + 255) & ~(size_t)255; return o; };
    const size_t o_Z      = alloc((size_t)nrows * CC * 2);       // bf16 Z
    const size_t o_coef   = alloc((size_t)nq * 64 * 4);
    const size_t o_amask  = alloc((size_t)nq * 4);
    const size_t o_flags  = alloc((size_t)nrows * 4);            // nrows*4 is 256-mult
    const size_t o_count  = alloc(256);                          // adjacent to flags
    const size_t o_list   = alloc((size_t)nrows * 4);
    const size_t o_WvT    = alloc(65536 * 2);
    const size_t o_WoutT  = alloc(65536 * 2);
    const size_t o_WoaT   = alloc(16384 * 2);
    const size_t need = cur;

    if (ws_size < need) {
        tda_fused<<<nq / QB, 256, 0, stream>>>(Fp, queries, idx_q, t_ref,
                                               W_off, b_off, W_attn, b_attn,
                                               W_v, b_v, W_out, b_out, out, LQV);
        return;
    }

    char* ws = (char*)d_ws;
    unsigned short* Z     = (unsigned short*)(ws + o_Z);
    float* coefW          = (float*)(ws + o_coef);
    int*   amaskW         = (int*)(ws + o_amask);
    int*   flags          = (int*)(ws + o_flags);
    int*   count          = (int*)(ws + o_count);
    int*   list           = (int*)(ws + o_list);
    unsigned short* WvT   = (unsigned short*)(ws + o_WvT);
    unsigned short* WoutT = (unsigned short*)(ws + o_WoutT);
    unsigned short* WoaT  = (unsigned short*)(ws + o_WoaT);

    // zero flags + count in ONE async memset (they are adjacent)
    hipMemsetAsync(flags, 0, (size_t)nrows * 4 + 256, stream);

    k0_prep<<<576, 256, 0, stream>>>(W_v, W_out, W_off, W_attn, WvT, WoutT, WoaT);
    k1b_offcoef<<<nq / 128, 256, 0, stream>>>(queries, WoaT, b_off, b_attn,
                                              idx_q, t_ref, coefW, amaskW, flags);
    k0d_compact<<<(nrows + 255) / 256, 256, 0, stream>>>(flags, count, list, nrows);
    k1_zgemm<<<(nrows + 127) / 128, 512, 0, stream>>>(Fp, WvT, count, list, Z);
    k2_final<<<nq / 16, 256, 0, stream>>>(Z, coefW, amaskW, idx_q, WoutT,
                                          b_v, b_out, out);
}

// Round 14
// 182.490 us; speedup vs baseline: 1.0996x; 1.0696x over previous
//
#include <hip/hip_runtime.h>
#include <hip/hip_bf16.h>

#define HH 8
#define KK 4
#define CC 256
#define TT 8
#define LQV 9216        // Lq == Lv (fixed problem shape)

typedef __attribute__((ext_vector_type(8))) short bf16x8;
typedef __attribute__((ext_vector_type(4))) float f32x4;

#define MFMA16(a, b, c) __builtin_amdgcn_mfma_f32_16x16x32_bf16(a, b, c, 0, 0, 0)

__device__ __forceinline__ unsigned short f2bf(float f) {
    union { float f; unsigned u; } v; v.f = f;
    unsigned r = v.u + 0x7fffu + ((v.u >> 16) & 1u);
    return (unsigned short)(r >> 16);
}
__device__ __forceinline__ float bf2f(unsigned short s) {
    union { unsigned u; float f; } v; v.u = ((unsigned)s) << 16;
    return v.f;
}

// ---------------------------------------------------------------------------
// K0: build bf16-transposed weights
//   WvT  [256 d][256 c] = W_v[c][d] ; WoutT likewise ; WoaT[64 n][256 c]
// ---------------------------------------------------------------------------
__global__ void k0_prep(const float* __restrict__ Wv, const float* __restrict__ Wout,
                        const float* __restrict__ Woff, const float* __restrict__ Wattn,
                        unsigned short* __restrict__ WvT, unsigned short* __restrict__ WoutT,
                        unsigned short* __restrict__ WoaT)
{
    int o = blockIdx.x * 256 + threadIdx.x;
    if (o < 65536) { int d = o >> 8, c = o & 255; WvT[o]   = f2bf(Wv[c * 256 + d]);   return; }
    o -= 65536;
    if (o < 65536) { int d = o >> 8, c = o & 255; WoutT[o] = f2bf(Wout[c * 256 + d]); return; }
    o -= 65536;
    if (o < 16384) {
        int n = o >> 8, c = o & 255;
        WoaT[o] = f2bf(n < 32 ? Woff[c * 32 + n] : Wattn[c * 32 + (n - 32)]);
    }
}

// ---------------------------------------------------------------------------
// K1b: offsets/logits GEMM fused with softmax -> coef/amask/flags
//   BM=128 queries, BN=64, 256 thr, 4 waves (2m x 2n). LDS union:
//   {A_s 10KB | B_s 5KB} during K-loop, olog[128][65] f32 (33.3KB) after.
// ---------------------------------------------------------------------------
__launch_bounds__(256, 2)
__global__ void k1b_offcoef(const float* __restrict__ queries, const unsigned short* __restrict__ WoaT,
                            const float* __restrict__ b_off, const float* __restrict__ b_attn,
                            const int* __restrict__ idx_q, const float* __restrict__ t_ref_q,
                            float* __restrict__ coefW, int* __restrict__ amaskW,
                            int* __restrict__ flags)
{
    __shared__ __attribute__((aligned(16))) char smem[128 * 65 * 4];   // 33.3 KB union
    unsigned short* A_s = (unsigned short*)smem;                 // [128][40]
    unsigned short* B_s = (unsigned short*)(smem + 128 * 40 * 2); // [64][40]
    float* olog = (float*)smem;                                  // [128][65]

    const int tid = threadIdx.x;
    const int q0 = blockIdx.x * 128;
    const int wid = tid >> 6, l = tid & 63;
    const int wm = wid >> 1, wn = wid & 1;

    f32x4 acc[4][2];
    #pragma unroll
    for (int i = 0; i < 4; ++i)
        #pragma unroll
        for (int j = 0; j < 2; ++j) acc[i][j] = (f32x4){0.f, 0.f, 0.f, 0.f};

    const int arow = tid >> 1, ahalf = tid & 1;      // A stage: 16 f32 each
    const int brow = tid >> 2, bq = tid & 3;         // B stage: 8 bf16 each
    const float* asrc = queries + (size_t)(q0 + arow) * CC + ahalf * 16;

    for (int ks = 0; ks < 8; ++ks) {
        const int k0 = ks * 32;
        {   // stage A (f32 -> bf16)
            float4 v0 = *(const float4*)(asrc + k0);
            float4 v1 = *(const float4*)(asrc + k0 + 4);
            float4 v2 = *(const float4*)(asrc + k0 + 8);
            float4 v3 = *(const float4*)(asrc + k0 + 12);
            bf16x8 p0, p1;
            p0[0]=f2bf(v0.x); p0[1]=f2bf(v0.y); p0[2]=f2bf(v0.z); p0[3]=f2bf(v0.w);
            p0[4]=f2bf(v1.x); p0[5]=f2bf(v1.y); p0[6]=f2bf(v1.z); p0[7]=f2bf(v1.w);
            p1[0]=f2bf(v2.x); p1[1]=f2bf(v2.y); p1[2]=f2bf(v2.z); p1[3]=f2bf(v2.w);
            p1[4]=f2bf(v3.x); p1[5]=f2bf(v3.y); p1[6]=f2bf(v3.z); p1[7]=f2bf(v3.w);
            *(bf16x8*)&A_s[arow * 40 + ahalf * 16]     = p0;
            *(bf16x8*)&A_s[arow * 40 + ahalf * 16 + 8] = p1;
        }
        {   // stage B (already bf16)
            *(bf16x8*)&B_s[brow * 40 + bq * 8] =
                *(const bf16x8*)&WoaT[brow * 256 + k0 + bq * 8];
        }
        __syncthreads();
        bf16x8 af[4], bfv[2];
        const int kb = (l >> 4) * 8, r0 = wm * 64 + (l & 15), c0 = wn * 32 + (l & 15);
        #pragma unroll
        for (int am = 0; am < 4; ++am) af[am] = *(bf16x8*)&A_s[(r0 + am * 16) * 40 + kb];
        #pragma unroll
        for (int bn = 0; bn < 2; ++bn) bfv[bn] = *(bf16x8*)&B_s[(c0 + bn * 16) * 40 + kb];
        #pragma unroll
        for (int am = 0; am < 4; ++am)
            #pragma unroll
            for (int bn = 0; bn < 2; ++bn)
                acc[am][bn] = MFMA16(af[am], bfv[bn], acc[am][bn]);
        __syncthreads();
    }

    // epilogue: acc (+bias) -> olog (LDS union; A_s/B_s dead after last sync)
    #pragma unroll
    for (int bn = 0; bn < 2; ++bn) {
        const int col = wn * 32 + bn * 16 + (l & 15);
        const float bias = (col < 32) ? b_off[col] : b_attn[col - 32];
        #pragma unroll
        for (int am = 0; am < 4; ++am)
            #pragma unroll
            for (int j = 0; j < 4; ++j) {
                const int lr = wm * 64 + am * 16 + (l >> 4) * 4 + j;
                olog[lr * 65 + col] = acc[am][bn][j] + bias;
            }
    }
    __syncthreads();

    // softmax + temporal coefficients (threads 0..127, one query each)
    if (tid < 128) {
        const int q = q0 + tid;
        const int b = q / LQV;
        const int idx = idx_q[q];
        const float tr = t_ref_q[q];
        const float* ol = olog + tid * 65;
        int am = 0;
        #pragma unroll
        for (int h = 0; h < HH; ++h) {
            float off[KK], lg[KK];
            #pragma unroll
            for (int k = 0; k < KK; ++k) { off[k] = ol[h * 4 + k]; lg[k] = ol[32 + h * 4 + k]; }
            float m = fmaxf(fmaxf(lg[0], lg[1]), fmaxf(lg[2], lg[3]));
            float e[KK], s = 0.f;
            #pragma unroll
            for (int k = 0; k < KK; ++k) { e[k] = expf(lg[k] - m); s += e[k]; }
            const float inv = 1.f / s;
            float crow[TT] = {0.f,0.f,0.f,0.f,0.f,0.f,0.f,0.f};
            #pragma unroll
            for (int k = 0; k < KK; ++k) {
                const float w = e[k] * inv;
                float ts = fminf(fmaxf(tr + off[k], 0.f), (float)(TT - 1));
                const int t0 = (int)ts;
                const int t1 = min(t0 + 1, TT - 1);
                const float a = ts - (float)t0;
                const float w0 = w * (1.f - a), w1 = w * a;
                #pragma unroll
                for (int t = 0; t < TT; ++t)
                    crow[t] += ((t == t0) ? w0 : 0.f) + ((t == t1) ? w1 : 0.f);
                am |= (1 << t0) | (1 << t1);
            }
            float4 c0 = {crow[0], crow[1], crow[2], crow[3]};
            float4 c1 = {crow[4], crow[5], crow[6], crow[7]};
            *(float4*)&coefW[(size_t)q * 64 + h * 8]     = c0;
            *(float4*)&coefW[(size_t)q * 64 + h * 8 + 4] = c1;
        }
        amaskW[q] = am;
        const int base = b * (TT * LQV) + idx;
        #pragma unroll
        for (int t = 0; t < TT; ++t)
            if ((am >> t) & 1) flags[base + t * LQV] = 1;
    }
}

// ---------------------------------------------------------------------------
// K0d: compact flagged rows into list
// ---------------------------------------------------------------------------
__global__ void k0d_compact(const int* __restrict__ flags, int* __restrict__ count,
                            int* __restrict__ list, int nrows)
{
    const int i = blockIdx.x * 256 + threadIdx.x;
    const bool p = (i < nrows) && (flags[i] != 0);
    const unsigned long long m = __ballot(p);
    const int lane = threadIdx.x & 63;
    const int lc = __popcll(m & ((1ull << lane) - 1ull));
    int base = 0;
    if (lane == 0) base = atomicAdd(count, __popcll(m));
    base = __shfl(base, 0);
    if (p) list[base + lc] = i;
}

// ---------------------------------------------------------------------------
// K1: Z[rho][:] = Fp[rho][:] @ W_v   (bf16 out, no bias) over compacted rows
//   BM=128 (list entries), BN=256, 512 thr, 8 waves 2m x 4n  (r11-verified)
// ---------------------------------------------------------------------------
__launch_bounds__(512, 2)
__global__ void k1_zgemm(const float* __restrict__ Fp, const unsigned short* __restrict__ WvT,
                         const int* __restrict__ count, const int* __restrict__ list,
                         unsigned short* __restrict__ Z)
{
    __shared__ __attribute__((aligned(16))) unsigned short A_s[128 * 40];  // 10 KB
    __shared__ __attribute__((aligned(16))) unsigned short B_s[256 * 40];  // 20 KB
    __shared__ int rows_s[128];
    const int cnt = count[0];
    const int bm0 = blockIdx.x * 128;
    if (bm0 >= cnt) return;
    const int tid = threadIdx.x;
    if (tid < 128) {
        const int i = bm0 + tid;
        rows_s[tid] = (i < cnt) ? list[i] : -1;
    }
    __syncthreads();
    const int wid = tid >> 6, l = tid & 63;
    const int wm = wid >> 2, wn = wid & 3;

    f32x4 acc[4][4];
    #pragma unroll
    for (int i = 0; i < 4; ++i)
        #pragma unroll
        for (int j = 0; j < 4; ++j) acc[i][j] = (f32x4){0.f, 0.f, 0.f, 0.f};

    const int arow = tid >> 2, aq = tid & 3;   // A stage: 8 f32 each
    const int brow = tid >> 1, bh = tid & 1;   // B stage: 16 bf16 each
    int rho = rows_s[arow]; if (rho < 0) rho = 0;
    const float* asrc = Fp + (size_t)rho * CC + aq * 8;

    for (int ks = 0; ks < 8; ++ks) {
        const int k0 = ks * 32;
        {   // stage A (f32 -> bf16)
            float4 v0 = *(const float4*)(asrc + k0);
            float4 v1 = *(const float4*)(asrc + k0 + 4);
            bf16x8 p;
            p[0]=f2bf(v0.x); p[1]=f2bf(v0.y); p[2]=f2bf(v0.z); p[3]=f2bf(v0.w);
            p[4]=f2bf(v1.x); p[5]=f2bf(v1.y); p[6]=f2bf(v1.z); p[7]=f2bf(v1.w);
            *(bf16x8*)&A_s[arow * 40 + aq * 8] = p;
        }
        {   // stage B (already bf16)
            *(bf16x8*)&B_s[brow * 40 + bh * 16]     = *(const bf16x8*)&WvT[brow * 256 + k0 + bh * 16];
            *(bf16x8*)&B_s[brow * 40 + bh * 16 + 8] = *(const bf16x8*)&WvT[brow * 256 + k0 + bh * 16 + 8];
        }
        __syncthreads();
        bf16x8 af[4], bfv[4];
        const int kb = (l >> 4) * 8, r0 = wm * 64 + (l & 15), c0 = wn * 64 + (l & 15);
        #pragma unroll
        for (int am = 0; am < 4; ++am) af[am] = *(bf16x8*)&A_s[(r0 + am * 16) * 40 + kb];
        #pragma unroll
        for (int bn = 0; bn < 4; ++bn) bfv[bn] = *(bf16x8*)&B_s[(c0 + bn * 16) * 40 + kb];
        #pragma unroll
        for (int am = 0; am < 4; ++am)
            #pragma unroll
            for (int bn = 0; bn < 4; ++bn)
                acc[am][bn] = MFMA16(af[am], bfv[bn], acc[am][bn]);
        __syncthreads();
    }
    // C write (bf16, scattered rows)
    #pragma unroll
    for (int am = 0; am < 4; ++am) {
        #pragma unroll
        for (int j = 0; j < 4; ++j) {
            const int trow = wm * 64 + am * 16 + (l >> 4) * 4 + j;
            const int r = rows_s[trow];
            if (r < 0) continue;
            #pragma unroll
            for (int bn = 0; bn < 4; ++bn) {
                const int col = wn * 64 + bn * 16 + (l & 15);
                Z[(size_t)r * CC + col] = f2bf(acc[am][bn][j]);
            }
        }
    }
}

// ---------------------------------------------------------------------------
// K2: gather Z rows (vectorized, coalesced), combine with coef (+b_v),
//     project with W_out (+b_out). Block = 16 queries, 256 thr.
// ---------------------------------------------------------------------------
__launch_bounds__(256, 4)
__global__ void k2_final(const unsigned short* __restrict__ Z, const float* __restrict__ coefW,
                         const int* __restrict__ amaskW, const int* __restrict__ idx_q,
                         const unsigned short* __restrict__ WoutT,
                         const float* __restrict__ b_v, const float* __restrict__ b_out,
                         float* __restrict__ out)
{
    __shared__ float coef_s[16 * 68];                                    // 4.25 KB
    __shared__ __attribute__((aligned(16))) unsigned short ho_s[16 * 264]; // 8.25 KB
    __shared__ int am_s[16];
    __shared__ int base_s[16];
    const int tid = threadIdx.x;
    const int q0 = blockIdx.x * 16;

    if (tid < 128) {   // coef: 16 q x 64, float4-vectorized
        const int iq = tid >> 3, qd = tid & 7;
        const float4 v0 = *(const float4*)&coefW[(size_t)(q0 + iq) * 64 + qd * 8];
        const float4 v1 = *(const float4*)&coefW[(size_t)(q0 + iq) * 64 + qd * 8 + 4];
        *(float4*)&coef_s[iq * 68 + qd * 8]     = v0;
        *(float4*)&coef_s[iq * 68 + qd * 8 + 4] = v1;
    } else if (tid < 144) {
        const int i = tid - 128;
        const int q = q0 + i;
        am_s[i] = amaskW[q];
        base_s[i] = (q / LQV) * (TT * LQV) + idx_q[q];
    }
    __syncthreads();

    // gather-combine: 32 lanes span one Z row (16B/lane), thread owns 8 ch
    const int g = tid & 31;          // channel group: channels g*8 .. g*8+7
    const int iq0 = tid >> 5;        // 0..7
    const float4 bv0 = *(const float4*)&b_v[g * 8];
    const float4 bv1 = *(const float4*)&b_v[g * 8 + 4];
    #pragma unroll
    for (int p = 0; p < 2; ++p) {
        const int iq = iq0 + 8 * p;
        const int am = am_s[iq];
        const int base = base_s[iq];
        const float* cf = &coef_s[iq * 68 + (g >> 2) * 8];   // head = g/4
        float acc[8] = {bv0.x, bv0.y, bv0.z, bv0.w, bv1.x, bv1.y, bv1.z, bv1.w};
        #pragma unroll
        for (int t = 0; t < TT; ++t) {
            if ((am >> t) & 1) {
                const float c = cf[t];
                const uint4 zv = *(const uint4*)&Z[(size_t)(base + t * LQV) * CC + g * 8];
                acc[0] += c * bf2f((unsigned short)(zv.x & 0xffffu));
                acc[1] += c * bf2f((unsigned short)(zv.x >> 16));
                acc[2] += c * bf2f((unsigned short)(zv.y & 0xffffu));
                acc[3] += c * bf2f((unsigned short)(zv.y >> 16));
                acc[4] += c * bf2f((unsigned short)(zv.z & 0xffffu));
                acc[5] += c * bf2f((unsigned short)(zv.z >> 16));
                acc[6] += c * bf2f((unsigned short)(zv.w & 0xffffu));
                acc[7] += c * bf2f((unsigned short)(zv.w >> 16));
            }
        }
        bf16x8 hp;
        #pragma unroll
        for (int j = 0; j < 8; ++j) hp[j] = (short)f2bf(acc[j]);
        *(bf16x8*)&ho_s[iq * 264 + g * 8] = hp;
    }
    __syncthreads();

    // out = HO @ W_out + b_out ; wave w owns n-tiles [w*4, w*4+4)
    const int wid = tid >> 6, l = tid & 63;
    const int kb = (l >> 4) * 8, r = l & 15;
    f32x4 acc[4];
    #pragma unroll
    for (int nt = 0; nt < 4; ++nt) acc[nt] = (f32x4){0.f, 0.f, 0.f, 0.f};
    for (int ks = 0; ks < 8; ++ks) {
        const bf16x8 a = *(bf16x8*)&ho_s[r * 264 + ks * 32 + kb];
        #pragma unroll
        for (int nt = 0; nt < 4; ++nt) {
            const int col = (wid * 4 + nt) * 16 + r;
            const bf16x8 bfr = *(const bf16x8*)&WoutT[(size_t)col * 256 + ks * 32 + kb];
            acc[nt] = MFMA16(a, bfr, acc[nt]);
        }
    }
    #pragma unroll
    for (int nt = 0; nt < 4; ++nt) {
        const int col = (wid * 4 + nt) * 16 + r;
        const float bo = b_out[col];
        #pragma unroll
        for (int j = 0; j < 4; ++j) {
            const int row = (l >> 4) * 4 + j;
            out[(size_t)(q0 + row) * CC + col] = acc[nt][j] + bo;
        }
    }
}

// ---------------------------------------------------------------------------
// Fallback: round-1 fused VALU kernel (used if ws is too small)
// ---------------------------------------------------------------------------
#define QB 8
__launch_bounds__(256, 2)
__global__ void tda_fused(const float* __restrict__ Fp, const float* __restrict__ queries,
                          const int* __restrict__ idx_q, const float* __restrict__ t_ref_q,
                          const float* __restrict__ W_off, const float* __restrict__ b_off,
                          const float* __restrict__ W_attn, const float* __restrict__ b_attn,
                          const float* __restrict__ W_v, const float* __restrict__ b_v,
                          const float* __restrict__ W_out, const float* __restrict__ b_out,
                          float* __restrict__ out, int Lv)
{
    __shared__ __attribute__((aligned(16))) float g_s[QB][HH][CC];
    __shared__ __attribute__((aligned(16))) float qho_s[QB][CC];
    __shared__ float offlog[QB][64];
    __shared__ float coef[QB][HH][TT];
    __shared__ float tref_s[QB];
    __shared__ int idx_s[QB];
    __shared__ int amask[QB];
    const int tid = threadIdx.x;
    const long qbase = (long)blockIdx.x * QB;
    const int b = (int)(qbase / LQV);
    #pragma unroll
    for (int i = 0; i < QB; ++i) qho_s[i][tid] = queries[(qbase + i) * CC + tid];
    if (tid < QB) { tref_s[tid] = t_ref_q[qbase + tid]; idx_s[tid] = idx_q[qbase + tid]; amask[tid] = 0; }
    { float* cfp = &coef[0][0][0]; cfp[tid] = 0.f; cfp[tid + 256] = 0.f; }
    __syncthreads();
    {
        const int o = tid & 63, i0 = tid >> 6, col = o & 31;
        const float* W = (o < 32) ? W_off : W_attn;
        const float bias = (o < 32) ? b_off[col] : b_attn[col];
        float acc0 = 0.f, acc1 = 0.f;
        for (int c = 0; c < CC; ++c) {
            const float w = W[c * 32 + col];
            acc0 += qho_s[i0][c] * w; acc1 += qho_s[i0 + 4][c] * w;
        }
        offlog[i0][o] = acc0 + bias; offlog[i0 + 4][o] = acc1 + bias;
    }
    __syncthreads();
    if (tid < QB * HH) {
        const int i = tid >> 3, h = tid & 7;
        float off[KK], lg[KK];
        #pragma unroll
        for (int k = 0; k < KK; ++k) { off[k] = offlog[i][h * KK + k]; lg[k] = offlog[i][32 + h * KK + k]; }
        float m = fmaxf(fmaxf(lg[0], lg[1]), fmaxf(lg[2], lg[3]));
        float e[KK], s = 0.f;
        #pragma unroll
        for (int k = 0; k < KK; ++k) { e[k] = expf(lg[k] - m); s += e[k]; }
        const float inv = 1.f / s;
        const float tr = tref_s[i];
        int mask = 0;
        #pragma unroll
        for (int k = 0; k < KK; ++k) {
            const float w = e[k] * inv;
            float ts = fminf(fmaxf(tr + off[k], 0.f), (float)(TT - 1));
            const int t0 = (int)ts; const int t1 = min(t0 + 1, TT - 1);
            const float a = ts - (float)t0;
            coef[i][h][t0] += w * (1.f - a); coef[i][h][t1] += w * a;
            mask |= (1 << t0) | (1 << t1);
        }
        atomicOr(&amask[i], mask);
    }
    __syncthreads();
    for (int i = 0; i < QB; ++i) {
        float g[HH] = {0.f,0.f,0.f,0.f,0.f,0.f,0.f,0.f};
        const int am = amask[i]; const int idx = idx_s[i];
        for (int t = 0; t < TT; ++t) {
            if ((am >> t) & 1) {
                const float rv = Fp[((long)(b * TT + t) * Lv + idx) * CC + tid];
                #pragma unroll
                for (int h = 0; h < HH; ++h) g[h] += coef[i][h][t] * rv;
            }
        }
        #pragma unroll
        for (int h = 0; h < HH; ++h) g_s[i][h][tid] = g[h];
    }
    __syncthreads();
    {
        const int h = tid >> 5;
        float acc[QB];
        #pragma unroll
        for (int i = 0; i < QB; ++i) acc[i] = b_v[tid];
        for (int c = 0; c < CC; c += 4) {
            const float w0 = W_v[(c + 0) * CC + tid], w1 = W_v[(c + 1) * CC + tid];
            const float w2 = W_v[(c + 2) * CC + tid], w3 = W_v[(c + 3) * CC + tid];
            #pragma unroll
            for (int i = 0; i < QB; ++i) {
                const float4 gv = *reinterpret_cast<const float4*>(&g_s[i][h][c]);
                acc[i] += gv.x * w0 + gv.y * w1 + gv.z * w2 + gv.w * w3;
            }
        }
        __syncthreads();
        #pragma unroll
        for (int i = 0; i < QB; ++i) qho_s[i][tid] = acc[i];
    }
    __syncthreads();
    {
        float acc[QB];
        #pragma unroll
        for (int i = 0; i < QB; ++i) acc[i] = b_out[tid];
        for (int c = 0; c < CC; c += 4) {
            const float w0 = W_out[(c + 0) * CC + tid], w1 = W_out[(c + 1) * CC + tid];
            const float w2 = W_out[(c + 2) * CC + tid], w3 = W_out[(c + 3) * CC + tid];
            #pragma unroll
            for (int i = 0; i < QB; ++i) {
                const float4 hv = *reinterpret_cast<const float4*>(&qho_s[i][c]);
                acc[i] += hv.x * w0 + hv.y * w1 + hv.z * w2 + hv.w * w3;
            }
        }
        #pragma unroll
        for (int i = 0; i < QB; ++i) out[(qbase + i) * CC + tid] = acc[i];
    }
}

// ---------------------------------------------------------------------------
extern "C" void kernel_launch(void* const* d_in, const int* in_sizes, int n_in,
                              void* d_out, int out_size, void* d_ws, size_t ws_size,
                              hipStream_t stream) {
    const float* Fp      = (const float*)d_in[0];
    const float* queries = (const float*)d_in[1];
    const int*   idx_q   = (const int*)d_in[2];
    const float* t_ref   = (const float*)d_in[3];
    const float* W_off   = (const float*)d_in[4];
    const float* b_off   = (const float*)d_in[5];
    const float* W_attn  = (const float*)d_in[6];
    const float* b_attn  = (const float*)d_in[7];
    const float* W_v     = (const float*)d_in[8];
    const float* b_v     = (const float*)d_in[9];
    const float* W_out   = (const float*)d_in[10];
    const float* b_out   = (const float*)d_in[11];
    float* out = (float*)d_out;

    const int nq    = in_sizes[2];            // B * Lq = 36864
    const int Bdim  = nq / LQV;               // 4
    const int nrows = Bdim * TT * LQV;        // 294912

    // workspace layout (flags+count adjacent -> single zeroing memset)
    size_t cur = 0;
    auto alloc = [&](size_t bytes) { size_t o = cur; cur += (bytes + 255) & ~(size_t)255; return o; };
    const size_t o_Z      = alloc((size_t)nrows * CC * 2);       // bf16 Z
    const size_t o_coef   = alloc((size_t)nq * 64 * 4);
    const size_t o_amask  = alloc((size_t)nq * 4);
    const size_t o_flags  = alloc((size_t)nrows * 4);            // nrows*4 is 256-mult
    const size_t o_count  = alloc(256);                          // adjacent to flags
    const size_t o_list   = alloc((size_t)nrows * 4);
    const size_t o_WvT    = alloc(65536 * 2);
    const size_t o_WoutT  = alloc(65536 * 2);
    const size_t o_WoaT   = alloc(16384 * 2);
    const size_t need = cur;

    if (ws_size < need) {
        tda_fused<<<nq / QB, 256, 0, stream>>>(Fp, queries, idx_q, t_ref,
                                               W_off, b_off, W_attn, b_attn,
                                               W_v, b_v, W_out, b_out, out, LQV);
        return;
    }

    char* ws = (char*)d_ws;
    unsigned short* Z     = (unsigned short*)(ws + o_Z);
    float* coefW          = (float*)(ws + o_coef);
    int*   amaskW         = (int*)(ws + o_amask);
    int*   flags          = (int*)(ws + o_flags);
    int*   count          = (int*)(ws + o_count);
    int*   list           = (int*)(ws + o_list);
    unsigned short* WvT   = (unsigned short*)(ws + o_WvT);
    unsigned short* WoutT = (unsigned short*)(ws + o_WoutT);
    unsigned short* WoaT  = (unsigned short*)(ws + o_WoaT);

    // zero flags + count in ONE async memset (they are adjacent)
    hipMemsetAsync(flags, 0, (size_t)nrows * 4 + 256, stream);

    k0_prep<<<576, 256, 0, stream>>>(W_v, W_out, W_off, W_attn, WvT, WoutT, WoaT);
    k1b_offcoef<<<nq / 128, 256, 0, stream>>>(queries, WoaT, b_off, b_attn,
                                              idx_q, t_ref, coefW, amaskW, flags);
    k0d_compact<<<(nrows + 255) / 256, 256, 0, stream>>>(flags, count, list, nrows);
    k1_zgemm<<<(nrows + 127) / 128, 512, 0, stream>>>(Fp, WvT, count, list, Z);
    k2_final<<<nq / 16, 256, 0, stream>>>(Z, coefW, amaskW, idx_q, WoutT,
                                          b_v, b_out, out);
}

// Round 15
// 178.636 us; speedup vs baseline: 1.1233x; 1.0216x over previous
//
#include <hip/hip_runtime.h>
#include <hip/hip_bf16.h>

#define HH 8
#define KK 4
#define CC 256
#define TT 8
#define LQV 9216        // Lq == Lv (fixed problem shape)

typedef __attribute__((ext_vector_type(8))) short bf16x8;
typedef __attribute__((ext_vector_type(4))) float f32x4;

#define MFMA16(a, b, c) __builtin_amdgcn_mfma_f32_16x16x32_bf16(a, b, c, 0, 0, 0)

__device__ __forceinline__ unsigned short f2bf(float f) {
    union { float f; unsigned u; } v; v.f = f;
    unsigned r = v.u + 0x7fffu + ((v.u >> 16) & 1u);
    return (unsigned short)(r >> 16);
}
__device__ __forceinline__ float bf2f(unsigned short s) {
    union { unsigned u; float f; } v; v.u = ((unsigned)s) << 16;
    return v.f;
}

// ---------------------------------------------------------------------------
// K0: build bf16-transposed weights
//   WvT  [256 d][256 c] = W_v[c][d] ; WoutT likewise ; WoaT[64 n][256 c]
// ---------------------------------------------------------------------------
__global__ void k0_prep(const float* __restrict__ Wv, const float* __restrict__ Wout,
                        const float* __restrict__ Woff, const float* __restrict__ Wattn,
                        unsigned short* __restrict__ WvT, unsigned short* __restrict__ WoutT,
                        unsigned short* __restrict__ WoaT)
{
    int o = blockIdx.x * 256 + threadIdx.x;
    if (o < 65536) { int d = o >> 8, c = o & 255; WvT[o]   = f2bf(Wv[c * 256 + d]);   return; }
    o -= 65536;
    if (o < 65536) { int d = o >> 8, c = o & 255; WoutT[o] = f2bf(Wout[c * 256 + d]); return; }
    o -= 65536;
    if (o < 16384) {
        int n = o >> 8, c = o & 255;
        WoaT[o] = f2bf(n < 32 ? Woff[c * 32 + n] : Wattn[c * 32 + (n - 32)]);
    }
}

// ---------------------------------------------------------------------------
// K1b: offsets/logits GEMM fused with softmax -> coef/amask/flags
//   (byte-identical to r11/r14, verified)
// ---------------------------------------------------------------------------
__launch_bounds__(256, 2)
__global__ void k1b_offcoef(const float* __restrict__ queries, const unsigned short* __restrict__ WoaT,
                            const float* __restrict__ b_off, const float* __restrict__ b_attn,
                            const int* __restrict__ idx_q, const float* __restrict__ t_ref_q,
                            float* __restrict__ coefW, int* __restrict__ amaskW,
                            int* __restrict__ flags)
{
    __shared__ __attribute__((aligned(16))) char smem[128 * 65 * 4];   // 33.3 KB union
    unsigned short* A_s = (unsigned short*)smem;                 // [128][40]
    unsigned short* B_s = (unsigned short*)(smem + 128 * 40 * 2); // [64][40]
    float* olog = (float*)smem;                                  // [128][65]

    const int tid = threadIdx.x;
    const int q0 = blockIdx.x * 128;
    const int wid = tid >> 6, l = tid & 63;
    const int wm = wid >> 1, wn = wid & 1;

    f32x4 acc[4][2];
    #pragma unroll
    for (int i = 0; i < 4; ++i)
        #pragma unroll
        for (int j = 0; j < 2; ++j) acc[i][j] = (f32x4){0.f, 0.f, 0.f, 0.f};

    const int arow = tid >> 1, ahalf = tid & 1;      // A stage: 16 f32 each
    const int brow = tid >> 2, bq = tid & 3;         // B stage: 8 bf16 each
    const float* asrc = queries + (size_t)(q0 + arow) * CC + ahalf * 16;

    for (int ks = 0; ks < 8; ++ks) {
        const int k0 = ks * 32;
        {   // stage A (f32 -> bf16)
            float4 v0 = *(const float4*)(asrc + k0);
            float4 v1 = *(const float4*)(asrc + k0 + 4);
            float4 v2 = *(const float4*)(asrc + k0 + 8);
            float4 v3 = *(const float4*)(asrc + k0 + 12);
            bf16x8 p0, p1;
            p0[0]=f2bf(v0.x); p0[1]=f2bf(v0.y); p0[2]=f2bf(v0.z); p0[3]=f2bf(v0.w);
            p0[4]=f2bf(v1.x); p0[5]=f2bf(v1.y); p0[6]=f2bf(v1.z); p0[7]=f2bf(v1.w);
            p1[0]=f2bf(v2.x); p1[1]=f2bf(v2.y); p1[2]=f2bf(v2.z); p1[3]=f2bf(v2.w);
            p1[4]=f2bf(v3.x); p1[5]=f2bf(v3.y); p1[6]=f2bf(v3.z); p1[7]=f2bf(v3.w);
            *(bf16x8*)&A_s[arow * 40 + ahalf * 16]     = p0;
            *(bf16x8*)&A_s[arow * 40 + ahalf * 16 + 8] = p1;
        }
        {   // stage B (already bf16)
            *(bf16x8*)&B_s[brow * 40 + bq * 8] =
                *(const bf16x8*)&WoaT[brow * 256 + k0 + bq * 8];
        }
        __syncthreads();
        bf16x8 af[4], bfv[2];
        const int kb = (l >> 4) * 8, r0 = wm * 64 + (l & 15), c0 = wn * 32 + (l & 15);
        #pragma unroll
        for (int am = 0; am < 4; ++am) af[am] = *(bf16x8*)&A_s[(r0 + am * 16) * 40 + kb];
        #pragma unroll
        for (int bn = 0; bn < 2; ++bn) bfv[bn] = *(bf16x8*)&B_s[(c0 + bn * 16) * 40 + kb];
        #pragma unroll
        for (int am = 0; am < 4; ++am)
            #pragma unroll
            for (int bn = 0; bn < 2; ++bn)
                acc[am][bn] = MFMA16(af[am], bfv[bn], acc[am][bn]);
        __syncthreads();
    }

    // epilogue: acc (+bias) -> olog (LDS union; A_s/B_s dead after last sync)
    #pragma unroll
    for (int bn = 0; bn < 2; ++bn) {
        const int col = wn * 32 + bn * 16 + (l & 15);
        const float bias = (col < 32) ? b_off[col] : b_attn[col - 32];
        #pragma unroll
        for (int am = 0; am < 4; ++am)
            #pragma unroll
            for (int j = 0; j < 4; ++j) {
                const int lr = wm * 64 + am * 16 + (l >> 4) * 4 + j;
                olog[lr * 65 + col] = acc[am][bn][j] + bias;
            }
    }
    __syncthreads();

    // softmax + temporal coefficients (threads 0..127, one query each)
    if (tid < 128) {
        const int q = q0 + tid;
        const int b = q / LQV;
        const int idx = idx_q[q];
        const float tr = t_ref_q[q];
        const float* ol = olog + tid * 65;
        int am = 0;
        #pragma unroll
        for (int h = 0; h < HH; ++h) {
            float off[KK], lg[KK];
            #pragma unroll
            for (int k = 0; k < KK; ++k) { off[k] = ol[h * 4 + k]; lg[k] = ol[32 + h * 4 + k]; }
            float m = fmaxf(fmaxf(lg[0], lg[1]), fmaxf(lg[2], lg[3]));
            float e[KK], s = 0.f;
            #pragma unroll
            for (int k = 0; k < KK; ++k) { e[k] = expf(lg[k] - m); s += e[k]; }
            const float inv = 1.f / s;
            float crow[TT] = {0.f,0.f,0.f,0.f,0.f,0.f,0.f,0.f};
            #pragma unroll
            for (int k = 0; k < KK; ++k) {
                const float w = e[k] * inv;
                float ts = fminf(fmaxf(tr + off[k], 0.f), (float)(TT - 1));
                const int t0 = (int)ts;
                const int t1 = min(t0 + 1, TT - 1);
                const float a = ts - (float)t0;
                const float w0 = w * (1.f - a), w1 = w * a;
                #pragma unroll
                for (int t = 0; t < TT; ++t)
                    crow[t] += ((t == t0) ? w0 : 0.f) + ((t == t1) ? w1 : 0.f);
                am |= (1 << t0) | (1 << t1);
            }
            float4 c0 = {crow[0], crow[1], crow[2], crow[3]};
            float4 c1 = {crow[4], crow[5], crow[6], crow[7]};
            *(float4*)&coefW[(size_t)q * 64 + h * 8]     = c0;
            *(float4*)&coefW[(size_t)q * 64 + h * 8 + 4] = c1;
        }
        amaskW[q] = am;
        const int base = b * (TT * LQV) + idx;
        #pragma unroll
        for (int t = 0; t < TT; ++t)
            if ((am >> t) & 1) flags[base + t * LQV] = 1;
    }
}

// ---------------------------------------------------------------------------
// K0d: compact flagged rows into list
// ---------------------------------------------------------------------------
__global__ void k0d_compact(const int* __restrict__ flags, int* __restrict__ count,
                            int* __restrict__ list, int nrows)
{
    const int i = blockIdx.x * 256 + threadIdx.x;
    const bool p = (i < nrows) && (flags[i] != 0);
    const unsigned long long m = __ballot(p);
    const int lane = threadIdx.x & 63;
    const int lc = __popcll(m & ((1ull << lane) - 1ull));
    int base = 0;
    if (lane == 0) base = atomicAdd(count, __popcll(m));
    base = __shfl(base, 0);
    if (p) list[base + lc] = i;
}

// ---------------------------------------------------------------------------
// K1 v4 (r15): r14 structure; B-staging switched to async global_load_lds.
//   B_s is LINEAR [256 rows][32 bf16] (gload_lds needs wave-uniform LDS base
//   + lane x 16B contiguity — padding would break it, m104/m173). Contents
//   bit-identical to r14's padded B_s. Wave w, issue i fills rows
//   [(2w+i)*16, +16): lane l -> row +(l>>2), chunk (l&3). Per-wave b128
//   reads of the linear tile distribute 8 words/bank = the 1KB wave-read
//   floor (same as pad-40). A-staging unchanged (needs f32->bf16 VALU).
// ---------------------------------------------------------------------------
__launch_bounds__(512, 2)
__global__ void k1_zgemm(const float* __restrict__ Fp, const unsigned short* __restrict__ WvT,
                         const int* __restrict__ count, const int* __restrict__ list,
                         unsigned short* __restrict__ Z)
{
    __shared__ __attribute__((aligned(16))) unsigned short A_s[128 * 40];  // 10 KB
    __shared__ __attribute__((aligned(16))) unsigned short B_s[256 * 32];  // 16 KB linear
    __shared__ int rows_s[128];
    const int cnt = count[0];
    const int bm0 = blockIdx.x * 128;
    if (bm0 >= cnt) return;
    const int tid = threadIdx.x;
    if (tid < 128) {
        const int i = bm0 + tid;
        rows_s[tid] = (i < cnt) ? list[i] : -1;
    }
    __syncthreads();
    const int wid = tid >> 6, l = tid & 63;
    const int wm = wid >> 2, wn = wid & 3;

    f32x4 acc[4][4];
    #pragma unroll
    for (int i = 0; i < 4; ++i)
        #pragma unroll
        for (int j = 0; j < 4; ++j) acc[i][j] = (f32x4){0.f, 0.f, 0.f, 0.f};

    const int arow = tid >> 2, aq = tid & 3;   // A stage: 8 f32 each
    int rho = rows_s[arow]; if (rho < 0) rho = 0;
    const float* asrc = Fp + (size_t)rho * CC + aq * 8;

    // B-staging geometry (per ks): wave wid issues 2 x 16B/lane
    const int bseg0 = wid * 2;                       // segments 0..15, 2 per wave
    const int brow_in_seg = l >> 2;                  // 0..15
    const int bchunk = l & 3;                        // 16B chunk in 64B row

    for (int ks = 0; ks < 8; ++ks) {
        const int k0 = ks * 32;
        {   // stage A (f32 -> bf16) — identical to r14
            float4 v0 = *(const float4*)(asrc + k0);
            float4 v1 = *(const float4*)(asrc + k0 + 4);
            bf16x8 p;
            p[0]=f2bf(v0.x); p[1]=f2bf(v0.y); p[2]=f2bf(v0.z); p[3]=f2bf(v0.w);
            p[4]=f2bf(v1.x); p[5]=f2bf(v1.y); p[6]=f2bf(v1.z); p[7]=f2bf(v1.w);
            *(bf16x8*)&A_s[arow * 40 + aq * 8] = p;
        }
        {   // stage B: async global->LDS, 16B per lane per issue
            #pragma unroll
            for (int i = 0; i < 2; ++i) {
                const int seg = bseg0 + i;                          // 0..15
                const int brow = seg * 16 + brow_in_seg;            // 0..255
                const unsigned short* src = &WvT[(size_t)brow * 256 + k0 + bchunk * 8];
                unsigned short* dst = &B_s[seg * 512];              // wave-uniform base
                __builtin_amdgcn_global_load_lds(
                    (const __attribute__((address_space(1))) unsigned int*)src,
                    (__attribute__((address_space(3))) unsigned int*)dst,
                    16, 0, 0);
            }
        }
        __syncthreads();   // compiler drains vmcnt+lgkmcnt before s_barrier
        bf16x8 af[4], bfv[4];
        const int kb = (l >> 4) * 8, r0 = wm * 64 + (l & 15), c0 = wn * 64 + (l & 15);
        #pragma unroll
        for (int am = 0; am < 4; ++am) af[am] = *(bf16x8*)&A_s[(r0 + am * 16) * 40 + kb];
        #pragma unroll
        for (int bn = 0; bn < 4; ++bn)
            bfv[bn] = *(bf16x8*)&B_s[(c0 + bn * 16) * 32 + kb];
        #pragma unroll
        for (int am = 0; am < 4; ++am)
            #pragma unroll
            for (int bn = 0; bn < 4; ++bn)
                acc[am][bn] = MFMA16(af[am], bfv[bn], acc[am][bn]);
        __syncthreads();
    }
    // C write (bf16, scattered rows) — identical to r14
    #pragma unroll
    for (int am = 0; am < 4; ++am) {
        #pragma unroll
        for (int j = 0; j < 4; ++j) {
            const int trow = wm * 64 + am * 16 + (l >> 4) * 4 + j;
            const int r = rows_s[trow];
            if (r < 0) continue;
            #pragma unroll
            for (int bn = 0; bn < 4; ++bn) {
                const int col = wn * 64 + bn * 16 + (l & 15);
                Z[(size_t)r * CC + col] = f2bf(acc[am][bn][j]);
            }
        }
    }
}

// ---------------------------------------------------------------------------
// K2: gather Z rows (vectorized, coalesced), combine with coef (+b_v),
//     project with W_out (+b_out). (byte-identical to r11/r14, verified)
// ---------------------------------------------------------------------------
__launch_bounds__(256, 4)
__global__ void k2_final(const unsigned short* __restrict__ Z, const float* __restrict__ coefW,
                         const int* __restrict__ amaskW, const int* __restrict__ idx_q,
                         const unsigned short* __restrict__ WoutT,
                         const float* __restrict__ b_v, const float* __restrict__ b_out,
                         float* __restrict__ out)
{
    __shared__ float coef_s[16 * 68];                                    // 4.25 KB
    __shared__ __attribute__((aligned(16))) unsigned short ho_s[16 * 264]; // 8.25 KB
    __shared__ int am_s[16];
    __shared__ int base_s[16];
    const int tid = threadIdx.x;
    const int q0 = blockIdx.x * 16;

    if (tid < 128) {   // coef: 16 q x 64, float4-vectorized
        const int iq = tid >> 3, qd = tid & 7;
        const float4 v0 = *(const float4*)&coefW[(size_t)(q0 + iq) * 64 + qd * 8];
        const float4 v1 = *(const float4*)&coefW[(size_t)(q0 + iq) * 64 + qd * 8 + 4];
        *(float4*)&coef_s[iq * 68 + qd * 8]     = v0;
        *(float4*)&coef_s[iq * 68 + qd * 8 + 4] = v1;
    } else if (tid < 144) {
        const int i = tid - 128;
        const int q = q0 + i;
        am_s[i] = amaskW[q];
        base_s[i] = (q / LQV) * (TT * LQV) + idx_q[q];
    }
    __syncthreads();

    // gather-combine: 32 lanes span one Z row (16B/lane), thread owns 8 ch
    const int g = tid & 31;          // channel group: channels g*8 .. g*8+7
    const int iq0 = tid >> 5;        // 0..7
    const float4 bv0 = *(const float4*)&b_v[g * 8];
    const float4 bv1 = *(const float4*)&b_v[g * 8 + 4];
    #pragma unroll
    for (int p = 0; p < 2; ++p) {
        const int iq = iq0 + 8 * p;
        const int am = am_s[iq];
        const int base = base_s[iq];
        const float* cf = &coef_s[iq * 68 + (g >> 2) * 8];   // head = g/4
        float acc[8] = {bv0.x, bv0.y, bv0.z, bv0.w, bv1.x, bv1.y, bv1.z, bv1.w};
        #pragma unroll
        for (int t = 0; t < TT; ++t) {
            if ((am >> t) & 1) {
                const float c = cf[t];
                const uint4 zv = *(const uint4*)&Z[(size_t)(base + t * LQV) * CC + g * 8];
                acc[0] += c * bf2f((unsigned short)(zv.x & 0xffffu));
                acc[1] += c * bf2f((unsigned short)(zv.x >> 16));
                acc[2] += c * bf2f((unsigned short)(zv.y & 0xffffu));
                acc[3] += c * bf2f((unsigned short)(zv.y >> 16));
                acc[4] += c * bf2f((unsigned short)(zv.z & 0xffffu));
                acc[5] += c * bf2f((unsigned short)(zv.z >> 16));
                acc[6] += c * bf2f((unsigned short)(zv.w & 0xffffu));
                acc[7] += c * bf2f((unsigned short)(zv.w >> 16));
            }
        }
        bf16x8 hp;
        #pragma unroll
        for (int j = 0; j < 8; ++j) hp[j] = (short)f2bf(acc[j]);
        *(bf16x8*)&ho_s[iq * 264 + g * 8] = hp;
    }
    __syncthreads();

    // out = HO @ W_out + b_out ; wave w owns n-tiles [w*4, w*4+4)
    const int wid = tid >> 6, l = tid & 63;
    const int kb = (l >> 4) * 8, r = l & 15;
    f32x4 acc[4];
    #pragma unroll
    for (int nt = 0; nt < 4; ++nt) acc[nt] = (f32x4){0.f, 0.f, 0.f, 0.f};
    for (int ks = 0; ks < 8; ++ks) {
        const bf16x8 a = *(bf16x8*)&ho_s[r * 264 + ks * 32 + kb];
        #pragma unroll
        for (int nt = 0; nt < 4; ++nt) {
            const int col = (wid * 4 + nt) * 16 + r;
            const bf16x8 bfr = *(const bf16x8*)&WoutT[(size_t)col * 256 + ks * 32 + kb];
            acc[nt] = MFMA16(a, bfr, acc[nt]);
        }
    }
    #pragma unroll
    for (int nt = 0; nt < 4; ++nt) {
        const int col = (wid * 4 + nt) * 16 + r;
        const float bo = b_out[col];
        #pragma unroll
        for (int j = 0; j < 4; ++j) {
            const int row = (l >> 4) * 4 + j;
            out[(size_t)(q0 + row) * CC + col] = acc[nt][j] + bo;
        }
    }
}

// ---------------------------------------------------------------------------
// Fallback: round-1 fused VALU kernel (used if ws is too small)
// ---------------------------------------------------------------------------
#define QB 8
__launch_bounds__(256, 2)
__global__ void tda_fused(const float* __restrict__ Fp, const float* __restrict__ queries,
                          const int* __restrict__ idx_q, const float* __restrict__ t_ref_q,
                          const float* __restrict__ W_off, const float* __restrict__ b_off,
                          const float* __restrict__ W_attn, const float* __restrict__ b_attn,
                          const float* __restrict__ W_v, const float* __restrict__ b_v,
                          const float* __restrict__ W_out, const float* __restrict__ b_out,
                          float* __restrict__ out, int Lv)
{
    __shared__ __attribute__((aligned(16))) float g_s[QB][HH][CC];
    __shared__ __attribute__((aligned(16))) float qho_s[QB][CC];
    __shared__ float offlog[QB][64];
    __shared__ float coef[QB][HH][TT];
    __shared__ float tref_s[QB];
    __shared__ int idx_s[QB];
    __shared__ int amask[QB];
    const int tid = threadIdx.x;
    const long qbase = (long)blockIdx.x * QB;
    const int b = (int)(qbase / LQV);
    #pragma unroll
    for (int i = 0; i < QB; ++i) qho_s[i][tid] = queries[(qbase + i) * CC + tid];
    if (tid < QB) { tref_s[tid] = t_ref_q[qbase + tid]; idx_s[tid] = idx_q[qbase + tid]; amask[tid] = 0; }
    { float* cfp = &coef[0][0][0]; cfp[tid] = 0.f; cfp[tid + 256] = 0.f; }
    __syncthreads();
    {
        const int o = tid & 63, i0 = tid >> 6, col = o & 31;
        const float* W = (o < 32) ? W_off : W_attn;
        const float bias = (o < 32) ? b_off[col] : b_attn[col];
        float acc0 = 0.f, acc1 = 0.f;
        for (int c = 0; c < CC; ++c) {
            const float w = W[c * 32 + col];
            acc0 += qho_s[i0][c] * w; acc1 += qho_s[i0 + 4][c] * w;
        }
        offlog[i0][o] = acc0 + bias; offlog[i0 + 4][o] = acc1 + bias;
    }
    __syncthreads();
    if (tid < QB * HH) {
        const int i = tid >> 3, h = tid & 7;
        float off[KK], lg[KK];
        #pragma unroll
        for (int k = 0; k < KK; ++k) { off[k] = offlog[i][h * KK + k]; lg[k] = offlog[i][32 + h * KK + k]; }
        float m = fmaxf(fmaxf(lg[0], lg[1]), fmaxf(lg[2], lg[3]));
        float e[KK], s = 0.f;
        #pragma unroll
        for (int k = 0; k < KK; ++k) { e[k] = expf(lg[k] - m); s += e[k]; }
        const float inv = 1.f / s;
        const float tr = tref_s[i];
        int mask = 0;
        #pragma unroll
        for (int k = 0; k < KK; ++k) {
            const float w = e[k] * inv;
            float ts = fminf(fmaxf(tr + off[k], 0.f), (float)(TT - 1));
            const int t0 = (int)ts; const int t1 = min(t0 + 1, TT - 1);
            const float a = ts - (float)t0;
            coef[i][h][t0] += w * (1.f - a); coef[i][h][t1] += w * a;
            mask |= (1 << t0) | (1 << t1);
        }
        atomicOr(&amask[i], mask);
    }
    __syncthreads();
    for (int i = 0; i < QB; ++i) {
        float g[HH] = {0.f,0.f,0.f,0.f,0.f,0.f,0.f,0.f};
        const int am = amask[i]; const int idx = idx_s[i];
        for (int t = 0; t < TT; ++t) {
            if ((am >> t) & 1) {
                const float rv = Fp[((long)(b * TT + t) * Lv + idx) * CC + tid];
                #pragma unroll
                for (int h = 0; h < HH; ++h) g[h] += coef[i][h][t] * rv;
            }
        }
        #pragma unroll
        for (int h = 0; h < HH; ++h) g_s[i][h][tid] = g[h];
    }
    __syncthreads();
    {
        const int h = tid >> 5;
        float acc[QB];
        #pragma unroll
        for (int i = 0; i < QB; ++i) acc[i] = b_v[tid];
        for (int c = 0; c < CC; c += 4) {
            const float w0 = W_v[(c + 0) * CC + tid], w1 = W_v[(c + 1) * CC + tid];
            const float w2 = W_v[(c + 2) * CC + tid], w3 = W_v[(c + 3) * CC + tid];
            #pragma unroll
            for (int i = 0; i < QB; ++i) {
                const float4 gv = *reinterpret_cast<const float4*>(&g_s[i][h][c]);
                acc[i] += gv.x * w0 + gv.y * w1 + gv.z * w2 + gv.w * w3;
            }
        }
        __syncthreads();
        #pragma unroll
        for (int i = 0; i < QB; ++i) qho_s[i][tid] = acc[i];
    }
    __syncthreads();
    {
        float acc[QB];
        #pragma unroll
        for (int i = 0; i < QB; ++i) acc[i] = b_out[tid];
        for (int c = 0; c < CC; c += 4) {
            const float w0 = W_out[(c + 0) * CC + tid], w1 = W_out[(c + 1) * CC + tid];
            const float w2 = W_out[(c + 2) * CC + tid], w3 = W_out[(c + 3) * CC + tid];
            #pragma unroll
            for (int i = 0; i < QB; ++i) {
                const float4 hv = *reinterpret_cast<const float4*>(&qho_s[i][c]);
                acc[i] += hv.x * w0 + hv.y * w1 + hv.z * w2 + hv.w * w3;
            }
        }
        #pragma unroll
        for (int i = 0; i < QB; ++i) out[(qbase + i) * CC + tid] = acc[i];
    }
}

// ---------------------------------------------------------------------------
extern "C" void kernel_launch(void* const* d_in, const int* in_sizes, int n_in,
                              void* d_out, int out_size, void* d_ws, size_t ws_size,
                              hipStream_t stream) {
    const float* Fp      = (const float*)d_in[0];
    const float* queries = (const float*)d_in[1];
    const int*   idx_q   = (const int*)d_in[2];
    const float* t_ref   = (const float*)d_in[3];
    const float* W_off   = (const float*)d_in[4];
    const float* b_off   = (const float*)d_in[5];
    const float* W_attn  = (const float*)d_in[6];
    const float* b_attn  = (const float*)d_in[7];
    const float* W_v     = (const float*)d_in[8];
    const float* b_v     = (const float*)d_in[9];
    const float* W_out   = (const float*)d_in[10];
    const float* b_out   = (const float*)d_in[11];
    float* out = (float*)d_out;

    const int nq    = in_sizes[2];            // B * Lq = 36864
    const int Bdim  = nq / LQV;               // 4
    const int nrows = Bdim * TT * LQV;        // 294912

    // workspace layout (flags+count adjacent -> single zeroing memset)
    size_t cur = 0;
    auto alloc = [&](size_t bytes) { size_t o = cur; cur += (bytes + 255) & ~(size_t)255; return o; };
    const size_t o_Z      = alloc((size_t)nrows * CC * 2);       // bf16 Z
    const size_t o_coef   = alloc((size_t)nq * 64 * 4);
    const size_t o_amask  = alloc((size_t)nq * 4);
    const size_t o_flags  = alloc((size_t)nrows * 4);            // nrows*4 is 256-mult
    const size_t o_count  = alloc(256);                          // adjacent to flags
    const size_t o_list   = alloc((size_t)nrows * 4);
    const size_t o_WvT    = alloc(65536 * 2);
    const size_t o_WoutT  = alloc(65536 * 2);
    const size_t o_WoaT   = alloc(16384 * 2);
    const size_t need = cur;

    if (ws_size < need) {
        tda_fused<<<nq / QB, 256, 0, stream>>>(Fp, queries, idx_q, t_ref,
                                               W_off, b_off, W_attn, b_attn,
                                               W_v, b_v, W_out, b_out, out, LQV);
        return;
    }

    char* ws = (char*)d_ws;
    unsigned short* Z     = (unsigned short*)(ws + o_Z);
    float* coefW          = (float*)(ws + o_coef);
    int*   amaskW         = (int*)(ws + o_amask);
    int*   flags          = (int*)(ws + o_flags);
    int*   count          = (int*)(ws + o_count);
    int*   list           = (int*)(ws + o_list);
    unsigned short* WvT   = (unsigned short*)(ws + o_WvT);
    unsigned short* WoutT = (unsigned short*)(ws + o_WoutT);
    unsigned short* WoaT  = (unsigned short*)(ws + o_WoaT);

    // zero flags + count in ONE async memset (they are adjacent)
    hipMemsetAsync(flags, 0, (size_t)nrows * 4 + 256, stream);

    k0_prep<<<576, 256, 0, stream>>>(W_v, W_out, W_off, W_attn, WvT, WoutT, WoaT);
    k1b_offcoef<<<nq / 128, 256, 0, stream>>>(queries, WoaT, b_off, b_attn,
                                              idx_q, t_ref, coefW, amaskW, flags);
    k0d_compact<<<(nrows + 255) / 256, 256, 0, stream>>>(flags, count, list, nrows);
    k1_zgemm<<<(nrows + 127) / 128, 512, 0, stream>>>(Fp, WvT, count, list, Z);
    k2_final<<<nq / 16, 256, 0, stream>>>(Z, coefW, amaskW, idx_q, WoutT,
                                          b_v, b_out, out);
}